// Round 5
// baseline (260.610 us; speedup 1.0000x reference)
//
#include <hip/hip_runtime.h>

#define NN 10000
#define NE 160000
#define TT 2
#define SS 2
#define HH 64
#define ZZ 32
#define KK 4
#define NIN 4

#define AGG_GRID 4096   // persistent single-wave blocks for the edge kernels

typedef short bf16x8 __attribute__((ext_vector_type(8)));
typedef float f32x4 __attribute__((ext_vector_type(4)));

// fp32 -> bf16 (RNE)
__device__ __forceinline__ unsigned short f2b(float x) {
    unsigned u = __float_as_uint(x);
    u += 0x7fffu + ((u >> 16) & 1u);
    return (unsigned short)(u >> 16);
}
__device__ __forceinline__ float bf2f(unsigned short u) {
    return __uint_as_float(((unsigned)u) << 16);
}

// leaky(dot(zG_row(bf16 pairs), qf[32]))
__device__ __forceinline__ float edge_score(const unsigned* __restrict__ zp,
                                            const float* __restrict__ qf) {
    float a = 0.f;
#pragma unroll
    for (int j = 0; j < 16; ++j) {
        unsigned u = zp[j];
        a += __uint_as_float(u << 16) * qf[2*j]
           + __uint_as_float(u & 0xffff0000u) * qf[2*j+1];
    }
    return a > 0.f ? a : 0.01f*a;
}

// P0: merged prep. blocks 0..15: attnM (MT[k][j][i], transposed). block 16: fold.
// blocks 17+: bf16 conversions + xt init + deg count.
__global__ __launch_bounds__(256) void k_prep(
    const float* __restrict__ Ws, const float* __restrict__ Wd,
    const float* __restrict__ F2w1, const float* __restrict__ xw,
    const float* __restrict__ xb, const float* __restrict__ F2w2,
    const float* __restrict__ F1w1, const float* __restrict__ F1w2,
    const float* __restrict__ ow1, const float* __restrict__ ow2,
    const float* __restrict__ zA, const float* __restrict__ zG,
    const float* __restrict__ inputs, const int* __restrict__ dst,
    float* __restrict__ MT, float* __restrict__ G1, float* __restrict__ G2,
    float* __restrict__ c1, float* __restrict__ c2,
    unsigned short* __restrict__ W2b, unsigned short* __restrict__ F1w1b,
    unsigned short* __restrict__ F1w2b, unsigned short* __restrict__ ow1b,
    unsigned short* __restrict__ ow2b, unsigned short* __restrict__ zAb,
    unsigned short* __restrict__ zGb, float* __restrict__ xt,
    int* __restrict__ deg_i)
{
    int b = blockIdx.x;
    int tid = threadIdx.x;
    if (b < 16) {
        int o = b*256 + tid;              // 4096 outputs
        int j = o & 31, i = (o >> 5) & 31, k = o >> 10;
        float acc = 0.0f;
        for (int h = 0; h < HH; ++h)
            acc += Ws[(k*HH + h)*ZZ + i] * Wd[(k*HH + h)*ZZ + j];
        MT[(k*ZZ + j)*ZZ + i] = acc;
    } else if (b == 16) {
        int h = tid >> 2, i = tid & 3;
        float a1 = 0.f, a2 = 0.f;
        for (int j = 0; j < HH; ++j) {
            float x = xw[j*NIN + i];
            a1 += F2w1[h*128 + j] * x;
            a2 += F2w1[h*128 + 64 + j] * x;
        }
        G1[h*4 + i] = a1;
        G2[h*4 + i] = a2;
        if (i == 0) {
            float b1 = 0.f, b2 = 0.f;
            for (int j = 0; j < HH; ++j) {
                float bb = xb[j];
                b1 += F2w1[h*128 + j] * bb;
                b2 += F2w1[h*128 + 64 + j] * bb;
            }
            c1[h] = b1; c2[h] = b2;
        }
    } else {
        int t = (b - 17)*256 + tid;
        if (t < NN*SS*ZZ) { zAb[t] = f2b(zA[t]); zGb[t] = f2b(zG[t]); }
        if (t < HH*HH)    { W2b[t] = f2b(F2w2[t]); F1w2b[t] = f2b(F1w2[t]); }
        if (t < HH*KK*HH) F1w1b[t] = f2b(F1w1[t]);
        if (t < HH*(HH+ZZ)) ow1b[t] = f2b(ow1[t]);
        if (t < 4*HH)     ow2b[t] = f2b(ow2[t]);
        if (t < NN*SS*NIN) {
            int i = t & 3;
            int n = t >> 3;
            xt[t] = inputs[n*(TT*NIN) + i];
        }
        if (t < NE) atomicAdd(deg_i + dst[t], 1);
    }
}

// C2: exclusive scan of deg_i -> offsets[0..NN], cursor copy (1 block, Hillis-Steele)
__global__ void k_scan(const int* __restrict__ deg_i, int* __restrict__ offsets,
                       int* __restrict__ cursor) {
    __shared__ int buf0[1024], buf1[1024];
    int tidx = threadIdx.x;
    const int CH = (NN + 1023) / 1024;   // 10
    int b0 = tidx * CH;
    int sum = 0;
    for (int i = 0; i < CH; ++i) { int idx = b0 + i; if (idx < NN) sum += deg_i[idx]; }
    buf0[tidx] = sum;
    __syncthreads();
    int* s = buf0; int* d = buf1;
    for (int off = 1; off < 1024; off <<= 1) {
        d[tidx] = s[tidx] + (tidx >= off ? s[tidx - off] : 0);
        __syncthreads();
        int* tmp = s; s = d; d = tmp;
    }
    int run = s[tidx] - sum;
    for (int i = 0; i < CH; ++i) {
        int idx = b0 + i;
        if (idx < NN) { offsets[idx] = run; cursor[idx] = run; run += deg_i[idx]; }
    }
    if (tidx == 0) offsets[NN] = NE;
}

// C3: scatter src node ids into dst-sorted position order
__global__ void k_scatter(const int* __restrict__ src, const int* __restrict__ dst,
                          int* __restrict__ cursor, int* __restrict__ src_by_pos) {
    int e = blockIdx.x * blockDim.x + threadIdx.x;
    if (e >= NE) return;
    int pos = atomicAdd(cursor + dst[e], 1);
    src_by_pos[pos] = src[e];
}

// Fused attention + step-0 aggregation. PERSISTENT single-wave blocks:
// grid = AGG_GRID, each wave grid-strides over items (interleaved -> degree
// skew averages out within a wave; items stay fully uncoupled across waves).
// This removes ~16K per-wave launch/drain cycles (R0-R4 invariant: 20K
// 1-wave blocks pinned at 44us regardless of body => churn-bound theory).
// Body per item identical to R0 + E-cache (exp reuse in pass 3).
__global__ __launch_bounds__(64) void k_attn_agg0(
    const float* __restrict__ MT, const float* __restrict__ zG,
    const unsigned short* __restrict__ zGb, const int* __restrict__ src_by_pos,
    const int* __restrict__ offsets, const float* __restrict__ xt,
    const float* __restrict__ G1, const float* __restrict__ G2,
    const float* __restrict__ c1, const float* __restrict__ c2,
    float* alpha, unsigned short* __restrict__ agg_b)
{
    __shared__ float sq[128];          // qd flat [k*32+i]
    __shared__ float alpha_s[64][4];   // alpha cache, first 64 edges
    int l = threadIdx.x;
    int i = l >> 2, k = l & 3;

    // hoisted per-lane invariants (L1/reg-resident across items)
    int h = l;
    const float4 g1 = *(const float4*)(G1 + h*4);
    const float4 g2 = *(const float4*)(G2 + h*4);
    float c1h = c1[h];
    float c2h = c2[h];

    for (int item = blockIdx.x; item < NN*SS; item += AGG_GRID) {
        int n = item >> 1, s = item & 1;
        int r0 = offsets[n], r1 = offsets[n+1];
        int deg = r1 - r0;

        // ---- phase 0: qd in-block (2 entries per lane) ----
        {
            int i0 = l & 31;
            int k0 = l >> 5;         // 0..1
            int k1 = k0 + 2;         // 2..3
            const float* zg = zG + item*ZZ;
            float acc0 = 0.f, acc1 = 0.f;
#pragma unroll
            for (int j = 0; j < ZZ; ++j) {
                float z = zg[j];
                acc0 += MT[(k0*ZZ + j)*ZZ + i0] * z;
                acc1 += MT[(k1*ZZ + j)*ZZ + i0] * z;
            }
            sq[k0*ZZ + i0] = acc0;
            sq[k1*ZZ + i0] = acc1;
        }
        __syncthreads();
        float qf[32];
#pragma unroll
        for (int j = 0; j < 32; ++j) qf[j] = sq[k*ZZ + j];

        // ---- phase 1: scores -> alpha ----
        float E[8];
        float mx = -1e30f;
        int nit = 0;
        for (int idx = r0 + i; idx < r1; idx += 16, ++nit) {
            int sn = src_by_pos[idx];
            float e = edge_score((const unsigned*)(zGb + (sn*SS + s)*ZZ), qf);
            if (nit < 8) E[nit] = e;
            mx = fmaxf(mx, e);
        }
#pragma unroll
        for (int off = 4; off < 64; off <<= 1) mx = fmaxf(mx, __shfl_xor(mx, off));
        float sum = 0.f;
        nit = 0;
        for (int idx = r0 + i; idx < r1; idx += 16, ++nit) {
            float e = (nit < 8) ? E[nit]
                    : edge_score((const unsigned*)(zGb + (src_by_pos[idx]*SS + s)*ZZ), qf);
            float ex = __expf(e - mx);
            if (nit < 8) E[nit] = ex;      // cache exp for pass 3
            sum += ex;
        }
#pragma unroll
        for (int off = 4; off < 64; off <<= 1) sum += __shfl_xor(sum, off);
        float dd = (float)(deg > 1 ? deg : 1);
        float inv = sum > 0.f ? 1.f/(sum*dd) : 0.f;
        nit = 0;
        for (int idx = r0 + i; idx < r1; idx += 16, ++nit) {
            float a = ((nit < 8) ? E[nit]
                     : __expf(edge_score((const unsigned*)(zGb + (src_by_pos[idx]*SS + s)*ZZ), qf) - mx)) * inv;
            alpha[(idx*2 + s)*4 + k] = a;
            int jo = idx - r0;
            if (jo < 64) alpha_s[jo][k] = a;
        }
        __syncthreads();

        // ---- phase 2: step-0 aggregation (lane = h), unrolled x4 ----
        const float4 xd = *(const float4*)(xt + item*4);
        float p2 = c2h + xd.x*g2.x + xd.y*g2.y + xd.z*g2.z + xd.w*g2.w;
        float a0 = 0.f, a1 = 0.f, a2 = 0.f, a3 = 0.f;
        int jo = 0;
        for (; jo + 4 <= deg; jo += 4) {
            int sn0 = src_by_pos[r0 + jo];
            int sn1 = src_by_pos[r0 + jo + 1];
            int sn2 = src_by_pos[r0 + jo + 2];
            int sn3 = src_by_pos[r0 + jo + 3];
            float4 x0 = *(const float4*)(xt + (sn0*SS + s)*NIN);
            float4 x1 = *(const float4*)(xt + (sn1*SS + s)*NIN);
            float4 x2 = *(const float4*)(xt + (sn2*SS + s)*NIN);
            float4 x3 = *(const float4*)(xt + (sn3*SS + s)*NIN);
            float4 w0 = (jo+0 < 64) ? *(const float4*)(&alpha_s[jo+0][0])
                                    : *(const float4*)(alpha + ((r0+jo+0)*2 + s)*4);
            float4 w1 = (jo+1 < 64) ? *(const float4*)(&alpha_s[jo+1][0])
                                    : *(const float4*)(alpha + ((r0+jo+1)*2 + s)*4);
            float4 w2 = (jo+2 < 64) ? *(const float4*)(&alpha_s[jo+2][0])
                                    : *(const float4*)(alpha + ((r0+jo+2)*2 + s)*4);
            float4 w3 = (jo+3 < 64) ? *(const float4*)(&alpha_s[jo+3][0])
                                    : *(const float4*)(alpha + ((r0+jo+3)*2 + s)*4);
            float p, hd;
            p = c1h + x0.x*g1.x + x0.y*g1.y + x0.z*g1.z + x0.w*g1.w;
            hd = p + p2; hd = hd > 0.f ? hd : 0.f;
            a0 += w0.x*hd; a1 += w0.y*hd; a2 += w0.z*hd; a3 += w0.w*hd;
            p = c1h + x1.x*g1.x + x1.y*g1.y + x1.z*g1.z + x1.w*g1.w;
            hd = p + p2; hd = hd > 0.f ? hd : 0.f;
            a0 += w1.x*hd; a1 += w1.y*hd; a2 += w1.z*hd; a3 += w1.w*hd;
            p = c1h + x2.x*g1.x + x2.y*g1.y + x2.z*g1.z + x2.w*g1.w;
            hd = p + p2; hd = hd > 0.f ? hd : 0.f;
            a0 += w2.x*hd; a1 += w2.y*hd; a2 += w2.z*hd; a3 += w2.w*hd;
            p = c1h + x3.x*g1.x + x3.y*g1.y + x3.z*g1.z + x3.w*g1.w;
            hd = p + p2; hd = hd > 0.f ? hd : 0.f;
            a0 += w3.x*hd; a1 += w3.y*hd; a2 += w3.z*hd; a3 += w3.w*hd;
        }
        for (; jo < deg; ++jo) {
            int sn = src_by_pos[r0 + jo];
            float4 x0 = *(const float4*)(xt + (sn*SS + s)*NIN);
            float4 w4 = (jo < 64) ? *(const float4*)(&alpha_s[jo][0])
                                  : *(const float4*)(alpha + ((r0+jo)*2 + s)*4);
            float p = c1h + x0.x*g1.x + x0.y*g1.y + x0.z*g1.z + x0.w*g1.w;
            float hd = p + p2; hd = hd > 0.f ? hd : 0.f;
            a0 += w4.x*hd; a1 += w4.y*hd; a2 += w4.z*hd; a3 += w4.w*hd;
        }
        agg_b[item*256 +       h] = f2b(a0);
        agg_b[item*256 + 64  + h] = f2b(a1);
        agg_b[item*256 + 128 + h] = f2b(a2);
        agg_b[item*256 + 192 + h] = f2b(a3);
        __syncthreads();   // protect sq/alpha_s reuse across items (1 wave: cheap)
    }
}

// B2: fused xenc + edge layer-1 + aggregation (step 1). Persistent single-wave
// blocks, grid-stride over items (same churn fix as attn).
__global__ __launch_bounds__(64) void k_agg2(
    const float* __restrict__ xt, const float* __restrict__ G1,
    const float* __restrict__ G2, const float* __restrict__ c1,
    const float* __restrict__ c2, const int* __restrict__ src_by_pos,
    const int* __restrict__ offsets, const float* __restrict__ alpha,
    unsigned short* __restrict__ agg_b)
{
    int h = threadIdx.x;
    const float4 g1 = *(const float4*)(G1 + h*4);
    const float4 g2 = *(const float4*)(G2 + h*4);
    float c1h = c1[h];
    float c2h = c2[h];

    for (int item = blockIdx.x; item < NN*SS; item += AGG_GRID) {
        int n = item >> 1, s = item & 1;
        int r0 = offsets[n], r1 = offsets[n+1];
        const float4 xd = *(const float4*)(xt + item*4);
        float p2 = c2h + xd.x*g2.x + xd.y*g2.y + xd.z*g2.z + xd.w*g2.w;
        float a0 = 0.f, a1 = 0.f, a2 = 0.f, a3 = 0.f;
        int idx = r0;
        for (; idx + 4 <= r1; idx += 4) {
            int sn0 = src_by_pos[idx];
            int sn1 = src_by_pos[idx+1];
            int sn2 = src_by_pos[idx+2];
            int sn3 = src_by_pos[idx+3];
            float4 x0 = *(const float4*)(xt + (sn0*SS + s)*NIN);
            float4 x1 = *(const float4*)(xt + (sn1*SS + s)*NIN);
            float4 x2 = *(const float4*)(xt + (sn2*SS + s)*NIN);
            float4 x3 = *(const float4*)(xt + (sn3*SS + s)*NIN);
            float4 w0 = *(const float4*)(alpha + ((idx+0)*2 + s)*4);
            float4 w1 = *(const float4*)(alpha + ((idx+1)*2 + s)*4);
            float4 w2 = *(const float4*)(alpha + ((idx+2)*2 + s)*4);
            float4 w3 = *(const float4*)(alpha + ((idx+3)*2 + s)*4);
            float p, hd;
            p = c1h + x0.x*g1.x + x0.y*g1.y + x0.z*g1.z + x0.w*g1.w;
            hd = p + p2; hd = hd > 0.f ? hd : 0.f;
            a0 += w0.x*hd; a1 += w0.y*hd; a2 += w0.z*hd; a3 += w0.w*hd;
            p = c1h + x1.x*g1.x + x1.y*g1.y + x1.z*g1.z + x1.w*g1.w;
            hd = p + p2; hd = hd > 0.f ? hd : 0.f;
            a0 += w1.x*hd; a1 += w1.y*hd; a2 += w1.z*hd; a3 += w1.w*hd;
            p = c1h + x2.x*g1.x + x2.y*g1.y + x2.z*g1.z + x2.w*g1.w;
            hd = p + p2; hd = hd > 0.f ? hd : 0.f;
            a0 += w2.x*hd; a1 += w2.y*hd; a2 += w2.z*hd; a3 += w2.w*hd;
            p = c1h + x3.x*g1.x + x3.y*g1.y + x3.z*g1.z + x3.w*g1.w;
            hd = p + p2; hd = hd > 0.f ? hd : 0.f;
            a0 += w3.x*hd; a1 += w3.y*hd; a2 += w3.z*hd; a3 += w3.w*hd;
        }
        for (; idx < r1; ++idx) {
            int sn = src_by_pos[idx];
            float4 x0 = *(const float4*)(xt + (sn*SS + s)*NIN);
            float4 w0 = *(const float4*)(alpha + (idx*2 + s)*4);
            float p = c1h + x0.x*g1.x + x0.y*g1.y + x0.z*g1.z + x0.w*g1.w;
            float hd = p + p2; hd = hd > 0.f ? hd : 0.f;
            a0 += w0.x*hd; a1 += w0.y*hd; a2 += w0.z*hd; a3 += w0.w*hd;
        }
        agg_b[item*256 +       h] = f2b(a0);
        agg_b[item*256 + 64  + h] = f2b(a1);
        agg_b[item*256 + 128 + h] = f2b(a2);
        agg_b[item*256 + 192 + h] = f2b(a3);
    }
}

// B3: GEMM0 (agg@W2^T block-diag per head) + chained node GEMMs.
// 4 waves/block, 16 items/wave. Per-wave LDS only, no barrier.
__global__ __launch_bounds__(256) void k_node_mfma(
    const unsigned short* __restrict__ agg_b, const unsigned short* __restrict__ zAb,
    const unsigned short* __restrict__ W2b,
    const unsigned short* __restrict__ F1w1b, const unsigned short* __restrict__ F1w2b,
    const unsigned short* __restrict__ ow1b, const unsigned short* __restrict__ ow2b,
    const float* __restrict__ ob1, const float* __restrict__ ob2,
    float* __restrict__ xt, float* __restrict__ out, int tstep)
{
    __shared__ unsigned short res_s[4][16*264];
    __shared__ unsigned short hid_s[4][16*72];
    __shared__ unsigned short hcat_s[4][16*104];
    int tid = threadIdx.x;
    int w = tid >> 6, l = tid & 63, l15 = l & 15, qq = l >> 4;

    bf16x8 w2f[2][4], b2f[2][4], o1f[3][4], bo2[2];
#pragma unroll
    for (int nb = 0; nb < 4; ++nb) {
        int n = nb*16 + l15;
#pragma unroll
        for (int kb = 0; kb < 2; ++kb) {
            w2f[kb][nb] = *(const bf16x8*)(W2b  + n*64 + kb*32 + qq*8);
            b2f[kb][nb] = *(const bf16x8*)(F1w2b + n*64 + kb*32 + qq*8);
        }
#pragma unroll
        for (int kb = 0; kb < 3; ++kb)
            o1f[kb][nb] = *(const bf16x8*)(ow1b + n*96 + kb*32 + qq*8);
    }
#pragma unroll
    for (int kb = 0; kb < 2; ++kb) {
        if (l15 < 4) bo2[kb] = *(const bf16x8*)(ow2b + l15*64 + kb*32 + qq*8);
        else {
            bf16x8 z;
#pragma unroll
            for (int j = 0; j < 8; ++j) z[j] = 0;
            bo2[kb] = z;
        }
    }
    float b1v[4];
#pragma unroll
    for (int nb = 0; nb < 4; ++nb) b1v[nb] = ob1[nb*16 + l15];
    float b2v = (l15 < 4) ? ob2[l15] : 0.0f;

    int itemBase = blockIdx.x*64 + w*16;
    if (itemBase >= NN*SS) return;

    *(uint4*)(&hcat_s[w][l15*104 + 64 + qq*8]) =
        *(const uint4*)(zAb + (itemBase + l15)*ZZ + qq*8);

    // GEMM0: res[item, k*64+h'] = sum_h agg[item,k*64+h] * W2[h'][h]
#pragma unroll
    for (int k = 0; k < 4; ++k) {
        f32x4 acc0[4];
#pragma unroll
        for (int nb = 0; nb < 4; ++nb) acc0[nb] = (f32x4)(0.0f);
#pragma unroll
        for (int kb = 0; kb < 2; ++kb) {
            bf16x8 af = *(const bf16x8*)(agg_b + (itemBase + l15)*256 + k*64 + kb*32 + qq*8);
#pragma unroll
            for (int nb = 0; nb < 4; ++nb)
                acc0[nb] = __builtin_amdgcn_mfma_f32_16x16x32_bf16(af, w2f[kb][nb], acc0[nb], 0, 0, 0);
        }
#pragma unroll
        for (int nb = 0; nb < 4; ++nb)
#pragma unroll
            for (int r = 0; r < 4; ++r)
                res_s[w][(qq*4 + r)*264 + k*64 + nb*16 + l15] = f2b(acc0[nb][r]);
    }

    // GEMM1: res[16x256] @ F1w1^T[256x64], relu
    f32x4 acc[4];
#pragma unroll
    for (int nb = 0; nb < 4; ++nb) acc[nb] = (f32x4)(0.0f);
#pragma unroll
    for (int kb = 0; kb < 8; ++kb) {
        bf16x8 af = *(const bf16x8*)(&res_s[w][l15*264 + kb*32 + qq*8]);
#pragma unroll
        for (int nb = 0; nb < 4; ++nb) {
            bf16x8 bf = *(const bf16x8*)(F1w1b + (nb*16 + l15)*256 + kb*32 + qq*8);
            acc[nb] = __builtin_amdgcn_mfma_f32_16x16x32_bf16(af, bf, acc[nb], 0, 0, 0);
        }
    }
#pragma unroll
    for (int nb = 0; nb < 4; ++nb)
#pragma unroll
        for (int r = 0; r < 4; ++r) {
            float v = acc[nb][r];
            hid_s[w][(qq*4 + r)*72 + nb*16 + l15] = f2b(v > 0.0f ? v : 0.0f);
        }

    // GEMM2: hid[16x64] @ F1w2^T[64x64] -> deltax -> hcat cols 0..63
    f32x4 acc2[4];
#pragma unroll
    for (int nb = 0; nb < 4; ++nb) acc2[nb] = (f32x4)(0.0f);
#pragma unroll
    for (int kb = 0; kb < 2; ++kb) {
        bf16x8 af = *(const bf16x8*)(&hid_s[w][l15*72 + kb*32 + qq*8]);
#pragma unroll
        for (int nb = 0; nb < 4; ++nb)
            acc2[nb] = __builtin_amdgcn_mfma_f32_16x16x32_bf16(af, b2f[kb][nb], acc2[nb], 0, 0, 0);
    }
#pragma unroll
    for (int nb = 0; nb < 4; ++nb)
#pragma unroll
        for (int r = 0; r < 4; ++r)
            hcat_s[w][(qq*4 + r)*104 + nb*16 + l15] = f2b(acc2[nb][r]);

    // GEMM3: hcat[16x96] @ ow1^T[96x64] + b1, relu -> hid_s
    f32x4 acc3[4];
#pragma unroll
    for (int nb = 0; nb < 4; ++nb) acc3[nb] = (f32x4)(0.0f);
#pragma unroll
    for (int kb = 0; kb < 3; ++kb) {
        bf16x8 af = *(const bf16x8*)(&hcat_s[w][l15*104 + kb*32 + qq*8]);
#pragma unroll
        for (int nb = 0; nb < 4; ++nb)
            acc3[nb] = __builtin_amdgcn_mfma_f32_16x16x32_bf16(af, o1f[kb][nb], acc3[nb], 0, 0, 0);
    }
#pragma unroll
    for (int nb = 0; nb < 4; ++nb)
#pragma unroll
        for (int r = 0; r < 4; ++r) {
            float v = acc3[nb][r] + b1v[nb];
            hid_s[w][(qq*4 + r)*72 + nb*16 + l15] = f2b(v > 0.0f ? v : 0.0f);
        }

    // GEMM4: hid[16x64] @ ow2^T[64x4(pad16)] + b2
    f32x4 acc4 = (f32x4)(0.0f);
#pragma unroll
    for (int kb = 0; kb < 2; ++kb) {
        bf16x8 af = *(const bf16x8*)(&hid_s[w][l15*72 + kb*32 + qq*8]);
        acc4 = __builtin_amdgcn_mfma_f32_16x16x32_bf16(af, bo2[kb], acc4, 0, 0, 0);
    }
    if (l15 < 4) {
#pragma unroll
        for (int r = 0; r < 4; ++r) {
            int item = itemBase + qq*4 + r;
            float nx = xt[item*4 + l15] + acc4[r] + b2v;
            xt[item*4 + l15] = nx;
            int n = item >> 1, s = item & 1;
            out[((n*TT + tstep)*SS + s)*4 + l15] = nx;
        }
    }
}

extern "C" void kernel_launch(void* const* d_in, const int* in_sizes, int n_in,
                              void* d_out, int out_size, void* d_ws, size_t ws_size,
                              hipStream_t stream) {
    const float* inputs = (const float*)d_in[0];
    const float* zA     = (const float*)d_in[1];
    const float* zG     = (const float*)d_in[2];
    const int*   src    = (const int*)d_in[3];
    const int*   dst    = (const int*)d_in[4];
    const float* Ws     = (const float*)d_in[5];
    const float* Wd     = (const float*)d_in[6];
    const float* F2w1   = (const float*)d_in[7];
    const float* F2w2   = (const float*)d_in[8];
    const float* F1w1   = (const float*)d_in[9];
    const float* F1w2   = (const float*)d_in[10];
    const float* xw     = (const float*)d_in[11];
    const float* xb     = (const float*)d_in[12];
    const float* ow1    = (const float*)d_in[13];
    const float* ob1    = (const float*)d_in[14];
    const float* ow2    = (const float*)d_in[15];
    const float* ob2    = (const float*)d_in[16];
    float* out = (float*)d_out;

    // ---- workspace carve (units: floats) ----
    float*          base        = (float*)d_ws;
    float*          MT          = base;                              // 4,096
    float*          alpha       = base + 4096;                       // 1,280,000
    int*            deg_i       = (int*)(base + 1284096);            // 10,000 (zeroed)
    int*            offsets     = (int*)(base + 1294096);            // 10,016
    int*            cursor      = (int*)(base + 1304112);            // 10,000
    int*            src_by_pos  = (int*)(base + 1314112);            // 160,000
    float*          xt          = base + 1474112;                    // 80,000
    float*          G1f         = base + 1554112;                    // 256
    float*          G2f         = base + 1554368;                    // 256
    float*          c1f         = base + 1554624;                    // 64
    float*          c2f         = base + 1554688;                    // 64 (pad to 1,554,816)
    unsigned short* W2b         = (unsigned short*)(base + 1554816); // 4,096 ush
    unsigned short* F1w1b       = (unsigned short*)(base + 1556864); // 16,384 ush
    unsigned short* F1w2b       = (unsigned short*)(base + 1565056); // 4,096 ush
    unsigned short* ow1b        = (unsigned short*)(base + 1567104); // 6,144 ush
    unsigned short* ow2b        = (unsigned short*)(base + 1570176); // 256 ush
    unsigned short* zAb         = (unsigned short*)(base + 1570304); // 640,000 ush
    unsigned short* zGb         = (unsigned short*)(base + 1890304); // 640,000 ush
    unsigned short* agg_b       = (unsigned short*)(base + 2210304); // 5,120,000 ush
    // total 4,770,304 floats = 19.1 MB

    hipMemsetAsync(deg_i, 0, 10000u * 4u, stream);

    // ---- attention phase (once) ----
    const int CONVB = (NN*SS*ZZ + 255)/256;   // 2500
    k_prep<<<17 + CONVB, 256, 0, stream>>>(Ws, Wd, F2w1, xw, xb, F2w2, F1w1, F1w2,
                                           ow1, ow2, zA, zG, inputs, dst,
                                           MT, G1f, G2f, c1f, c2f,
                                           W2b, F1w1b, F1w2b, ow1b, ow2b,
                                           zAb, zGb, xt, deg_i);
    k_scan<<<1, 1024, 0, stream>>>(deg_i, offsets, cursor);
    k_scatter<<<(NE + 255)/256, 256, 0, stream>>>(src, dst, cursor, src_by_pos);

    // ---- step 0 (attention fused with aggregation) ----
    k_attn_agg0<<<AGG_GRID, 64, 0, stream>>>(MT, zG, zGb, src_by_pos, offsets, xt,
                                             G1f, G2f, c1f, c2f, alpha, agg_b);
    k_node_mfma<<<(NN*SS + 63)/64, 256, 0, stream>>>(agg_b, zAb, W2b, F1w1b, F1w2b,
                                                     ow1b, ow2b, ob1, ob2, xt, out, 0);
    // ---- step 1 ----
    k_agg2<<<AGG_GRID, 64, 0, stream>>>(xt, G1f, G2f, c1f, c2f,
                                        src_by_pos, offsets, alpha, agg_b);
    k_node_mfma<<<(NN*SS + 63)/64, 256, 0, stream>>>(agg_b, zAb, W2b, F1w1b, F1w2b,
                                                     ow1b, ow2b, ob1, ob2, xt, out, 1);
}

// Round 6
// 226.714 us; speedup vs baseline: 1.1495x; 1.1495x over previous
//
#include <hip/hip_runtime.h>

#define NN 10000
#define NE 160000
#define TT 2
#define SS 2
#define HH 64
#define ZZ 32
#define KK 4
#define NIN 4

typedef short bf16x8 __attribute__((ext_vector_type(8)));
typedef float f32x4 __attribute__((ext_vector_type(4)));

// fp32 -> bf16 (RNE)
__device__ __forceinline__ unsigned short f2b(float x) {
    unsigned u = __float_as_uint(x);
    u += 0x7fffu + ((u >> 16) & 1u);
    return (unsigned short)(u >> 16);
}
__device__ __forceinline__ float bf2f(unsigned short u) {
    return __uint_as_float(((unsigned)u) << 16);
}

// wave-local LDS fence for single-wave blocks: wait DS ops only (NOT vmem),
// forbid compiler reordering. Replaces __syncthreads, whose s_waitcnt vmcnt(0)
// would put the pass-3 global alpha stores on the per-item critical path.
__device__ __forceinline__ void wave_lds_fence() {
    asm volatile("s_waitcnt lgkmcnt(0)" ::: "memory");
    __builtin_amdgcn_wave_barrier();
}

// leaky(dot(zG_row(bf16 pairs), qf[32]))
__device__ __forceinline__ float edge_score(const unsigned* __restrict__ zp,
                                            const float* __restrict__ qf) {
    float a = 0.f;
#pragma unroll
    for (int j = 0; j < 16; ++j) {
        unsigned u = zp[j];
        a += __uint_as_float(u << 16) * qf[2*j]
           + __uint_as_float(u & 0xffff0000u) * qf[2*j+1];
    }
    return a > 0.f ? a : 0.01f*a;
}

// P0: merged prep. blocks 0..15: attnM (MT[k][j][i], transposed). block 16: fold.
// blocks 17+: bf16 conversions + xt init + deg count.
__global__ __launch_bounds__(256) void k_prep(
    const float* __restrict__ Ws, const float* __restrict__ Wd,
    const float* __restrict__ F2w1, const float* __restrict__ xw,
    const float* __restrict__ xb, const float* __restrict__ F2w2,
    const float* __restrict__ F1w1, const float* __restrict__ F1w2,
    const float* __restrict__ ow1, const float* __restrict__ ow2,
    const float* __restrict__ zA, const float* __restrict__ zG,
    const float* __restrict__ inputs, const int* __restrict__ dst,
    float* __restrict__ MT, float* __restrict__ G1, float* __restrict__ G2,
    float* __restrict__ c1, float* __restrict__ c2,
    unsigned short* __restrict__ W2b, unsigned short* __restrict__ F1w1b,
    unsigned short* __restrict__ F1w2b, unsigned short* __restrict__ ow1b,
    unsigned short* __restrict__ ow2b, unsigned short* __restrict__ zAb,
    unsigned short* __restrict__ zGb, float* __restrict__ xt,
    int* __restrict__ deg_i)
{
    int b = blockIdx.x;
    int tid = threadIdx.x;
    if (b < 16) {
        int o = b*256 + tid;              // 4096 outputs
        int j = o & 31, i = (o >> 5) & 31, k = o >> 10;
        float acc = 0.0f;
        for (int h = 0; h < HH; ++h)
            acc += Ws[(k*HH + h)*ZZ + i] * Wd[(k*HH + h)*ZZ + j];
        MT[(k*ZZ + j)*ZZ + i] = acc;
    } else if (b == 16) {
        int h = tid >> 2, i = tid & 3;
        float a1 = 0.f, a2 = 0.f;
        for (int j = 0; j < HH; ++j) {
            float x = xw[j*NIN + i];
            a1 += F2w1[h*128 + j] * x;
            a2 += F2w1[h*128 + 64 + j] * x;
        }
        G1[h*4 + i] = a1;
        G2[h*4 + i] = a2;
        if (i == 0) {
            float b1 = 0.f, b2 = 0.f;
            for (int j = 0; j < HH; ++j) {
                float bb = xb[j];
                b1 += F2w1[h*128 + j] * bb;
                b2 += F2w1[h*128 + 64 + j] * bb;
            }
            c1[h] = b1; c2[h] = b2;
        }
    } else {
        int t = (b - 17)*256 + tid;
        if (t < NN*SS*ZZ) { zAb[t] = f2b(zA[t]); zGb[t] = f2b(zG[t]); }
        if (t < HH*HH)    { W2b[t] = f2b(F2w2[t]); F1w2b[t] = f2b(F1w2[t]); }
        if (t < HH*KK*HH) F1w1b[t] = f2b(F1w1[t]);
        if (t < HH*(HH+ZZ)) ow1b[t] = f2b(ow1[t]);
        if (t < 4*HH)     ow2b[t] = f2b(ow2[t]);
        if (t < NN*SS*NIN) {
            int i = t & 3;
            int n = t >> 3;
            xt[t] = inputs[n*(TT*NIN) + i];
        }
        if (t < NE) atomicAdd(deg_i + dst[t], 1);
    }
}

// C2: exclusive scan of deg_i -> offsets[0..NN], cursor copy (1 block, Hillis-Steele)
__global__ void k_scan(const int* __restrict__ deg_i, int* __restrict__ offsets,
                       int* __restrict__ cursor) {
    __shared__ int buf0[1024], buf1[1024];
    int tidx = threadIdx.x;
    const int CH = (NN + 1023) / 1024;   // 10
    int b0 = tidx * CH;
    int sum = 0;
    for (int i = 0; i < CH; ++i) { int idx = b0 + i; if (idx < NN) sum += deg_i[idx]; }
    buf0[tidx] = sum;
    __syncthreads();
    int* s = buf0; int* d = buf1;
    for (int off = 1; off < 1024; off <<= 1) {
        d[tidx] = s[tidx] + (tidx >= off ? s[tidx - off] : 0);
        __syncthreads();
        int* tmp = s; s = d; d = tmp;
    }
    int run = s[tidx] - sum;
    for (int i = 0; i < CH; ++i) {
        int idx = b0 + i;
        if (idx < NN) { offsets[idx] = run; cursor[idx] = run; run += deg_i[idx]; }
    }
    if (tidx == 0) offsets[NN] = NE;
}

// C3: scatter src node ids into dst-sorted position order
__global__ void k_scatter(const int* __restrict__ src, const int* __restrict__ dst,
                          int* __restrict__ cursor, int* __restrict__ src_by_pos) {
    int e = blockIdx.x * blockDim.x + threadIdx.x;
    if (e >= NE) return;
    int pos = atomicAdd(cursor + dst[e], 1);
    src_by_pos[pos] = src[e];
}

// Fused attention + step-0 aggregation. One 64-thread block per (n,s) item
// (R0 geometry — proven; R1/R3/R5 alternatives all regressed).
// Phase 0: qd in-block (padded sq: k*33+j kills the 4-way bank conflict on the
// qf fill). Phase 1: scores -> alpha; E[] caches raw scores then exp values so
// passes 2/3 are register-only for deg<=128. Phase boundaries use wave-local
// LDS fences instead of __syncthreads: the only cross-phase deps are LDS, and
// the barrier's vmcnt(0) would serialize the alpha global stores into the
// per-item critical path (R6 theory: that drain IS the 44us floor).
__global__ __launch_bounds__(64) void k_attn_agg0(
    const float* __restrict__ MT, const float* __restrict__ zG,
    const unsigned short* __restrict__ zGb, const int* __restrict__ src_by_pos,
    const int* __restrict__ offsets, const float* __restrict__ xt,
    const float* __restrict__ G1, const float* __restrict__ G2,
    const float* __restrict__ c1, const float* __restrict__ c2,
    float* alpha, unsigned short* __restrict__ agg_b)
{
    __shared__ float sq[132];          // qd flat [k*33+j] (+1 pad per row)
    __shared__ float alpha_s[64][4];   // alpha cache, first 64 edges
    int item = blockIdx.x;
    int n = item >> 1, s = item & 1;
    int l = threadIdx.x;
    int i = l >> 2, k = l & 3;
    int r0 = offsets[n], r1 = offsets[n+1];

    // ---- phase 0: qd in-block (2 entries per lane) ----
    {
        int i0 = l & 31;
        int k0 = l >> 5;         // 0..1
        int k1 = k0 + 2;         // 2..3
        const float* zg = zG + item*ZZ;
        float acc0 = 0.f, acc1 = 0.f;
#pragma unroll
        for (int j = 0; j < ZZ; ++j) {
            float z = zg[j];
            acc0 += MT[(k0*ZZ + j)*ZZ + i0] * z;
            acc1 += MT[(k1*ZZ + j)*ZZ + i0] * z;
        }
        sq[k0*33 + i0] = acc0;
        sq[k1*33 + i0] = acc1;
    }
    wave_lds_fence();
    float qf[32];
#pragma unroll
    for (int j = 0; j < 32; ++j) qf[j] = sq[k*33 + j];

    // ---- phase 1: scores -> alpha ----
    float E[8];
    float mx = -1e30f;
    int nit = 0;
    for (int idx = r0 + i; idx < r1; idx += 16, ++nit) {
        int sn = src_by_pos[idx];
        float e = edge_score((const unsigned*)(zGb + (sn*SS + s)*ZZ), qf);
        if (nit < 8) E[nit] = e;
        mx = fmaxf(mx, e);
    }
#pragma unroll
    for (int off = 4; off < 64; off <<= 1) mx = fmaxf(mx, __shfl_xor(mx, off));
    float sum = 0.f;
    nit = 0;
    for (int idx = r0 + i; idx < r1; idx += 16, ++nit) {
        float e = (nit < 8) ? E[nit]
                : edge_score((const unsigned*)(zGb + (src_by_pos[idx]*SS + s)*ZZ), qf);
        float ex = __expf(e - mx);
        if (nit < 8) E[nit] = ex;      // cache exp for pass 3
        sum += ex;
    }
#pragma unroll
    for (int off = 4; off < 64; off <<= 1) sum += __shfl_xor(sum, off);
    int deg = r1 - r0;
    float dd = (float)(deg > 1 ? deg : 1);
    float inv = sum > 0.f ? 1.f/(sum*dd) : 0.f;
    nit = 0;
    for (int idx = r0 + i; idx < r1; idx += 16, ++nit) {
        float a = ((nit < 8) ? E[nit]
                 : __expf(edge_score((const unsigned*)(zGb + (src_by_pos[idx]*SS + s)*ZZ), qf) - mx)) * inv;
        alpha[(idx*2 + s)*4 + k] = a;
        int jo = idx - r0;
        if (jo < 64) alpha_s[jo][k] = a;
    }
    wave_lds_fence();   // LDS-only dep; alpha global stores drain during phase 2

    // ---- phase 2: step-0 aggregation (lane = h), unrolled x4 ----
    int h = l;
    const float4 g1 = *(const float4*)(G1 + h*4);
    const float4 g2 = *(const float4*)(G2 + h*4);
    const float4 xd = *(const float4*)(xt + item*4);
    float p2 = c2[h] + xd.x*g2.x + xd.y*g2.y + xd.z*g2.z + xd.w*g2.w;
    float c1h = c1[h];
    float a0 = 0.f, a1 = 0.f, a2 = 0.f, a3 = 0.f;
    int jo = 0;
    for (; jo + 4 <= deg; jo += 4) {
        int sn0 = src_by_pos[r0 + jo];
        int sn1 = src_by_pos[r0 + jo + 1];
        int sn2 = src_by_pos[r0 + jo + 2];
        int sn3 = src_by_pos[r0 + jo + 3];
        float4 x0 = *(const float4*)(xt + (sn0*SS + s)*NIN);
        float4 x1 = *(const float4*)(xt + (sn1*SS + s)*NIN);
        float4 x2 = *(const float4*)(xt + (sn2*SS + s)*NIN);
        float4 x3 = *(const float4*)(xt + (sn3*SS + s)*NIN);
        float4 w0 = (jo+0 < 64) ? *(const float4*)(&alpha_s[jo+0][0])
                                : *(const float4*)(alpha + ((r0+jo+0)*2 + s)*4);
        float4 w1 = (jo+1 < 64) ? *(const float4*)(&alpha_s[jo+1][0])
                                : *(const float4*)(alpha + ((r0+jo+1)*2 + s)*4);
        float4 w2 = (jo+2 < 64) ? *(const float4*)(&alpha_s[jo+2][0])
                                : *(const float4*)(alpha + ((r0+jo+2)*2 + s)*4);
        float4 w3 = (jo+3 < 64) ? *(const float4*)(&alpha_s[jo+3][0])
                                : *(const float4*)(alpha + ((r0+jo+3)*2 + s)*4);
        float p, hd;
        p = c1h + x0.x*g1.x + x0.y*g1.y + x0.z*g1.z + x0.w*g1.w;
        hd = p + p2; hd = hd > 0.f ? hd : 0.f;
        a0 += w0.x*hd; a1 += w0.y*hd; a2 += w0.z*hd; a3 += w0.w*hd;
        p = c1h + x1.x*g1.x + x1.y*g1.y + x1.z*g1.z + x1.w*g1.w;
        hd = p + p2; hd = hd > 0.f ? hd : 0.f;
        a0 += w1.x*hd; a1 += w1.y*hd; a2 += w1.z*hd; a3 += w1.w*hd;
        p = c1h + x2.x*g1.x + x2.y*g1.y + x2.z*g1.z + x2.w*g1.w;
        hd = p + p2; hd = hd > 0.f ? hd : 0.f;
        a0 += w2.x*hd; a1 += w2.y*hd; a2 += w2.z*hd; a3 += w2.w*hd;
        p = c1h + x3.x*g1.x + x3.y*g1.y + x3.z*g1.z + x3.w*g1.w;
        hd = p + p2; hd = hd > 0.f ? hd : 0.f;
        a0 += w3.x*hd; a1 += w3.y*hd; a2 += w3.z*hd; a3 += w3.w*hd;
    }
    for (; jo < deg; ++jo) {
        int sn = src_by_pos[r0 + jo];
        float4 x0 = *(const float4*)(xt + (sn*SS + s)*NIN);
        float4 w4 = (jo < 64) ? *(const float4*)(&alpha_s[jo][0])
                              : *(const float4*)(alpha + ((r0+jo)*2 + s)*4);
        float p = c1h + x0.x*g1.x + x0.y*g1.y + x0.z*g1.z + x0.w*g1.w;
        float hd = p + p2; hd = hd > 0.f ? hd : 0.f;
        a0 += w4.x*hd; a1 += w4.y*hd; a2 += w4.z*hd; a3 += w4.w*hd;
    }
    agg_b[item*256 +       h] = f2b(a0);
    agg_b[item*256 + 64  + h] = f2b(a1);
    agg_b[item*256 + 128 + h] = f2b(a2);
    agg_b[item*256 + 192 + h] = f2b(a3);
}

// B2: fused xenc + edge layer-1 + aggregation (step 1). One 64-thread block
// per item. Edge loop unrolled x4.
__global__ __launch_bounds__(64) void k_agg2(
    const float* __restrict__ xt, const float* __restrict__ G1,
    const float* __restrict__ G2, const float* __restrict__ c1,
    const float* __restrict__ c2, const int* __restrict__ src_by_pos,
    const int* __restrict__ offsets, const float* __restrict__ alpha,
    unsigned short* __restrict__ agg_b)
{
    int item = blockIdx.x;
    int n = item >> 1, s = item & 1;
    int h = threadIdx.x;
    int r0 = offsets[n], r1 = offsets[n+1];
    const float4 g1 = *(const float4*)(G1 + h*4);
    const float4 g2 = *(const float4*)(G2 + h*4);
    const float4 xd = *(const float4*)(xt + item*4);
    float p2 = c2[h] + xd.x*g2.x + xd.y*g2.y + xd.z*g2.z + xd.w*g2.w;
    float c1h = c1[h];
    float a0 = 0.f, a1 = 0.f, a2 = 0.f, a3 = 0.f;
    int idx = r0;
    for (; idx + 4 <= r1; idx += 4) {
        int sn0 = src_by_pos[idx];
        int sn1 = src_by_pos[idx+1];
        int sn2 = src_by_pos[idx+2];
        int sn3 = src_by_pos[idx+3];
        float4 x0 = *(const float4*)(xt + (sn0*SS + s)*NIN);
        float4 x1 = *(const float4*)(xt + (sn1*SS + s)*NIN);
        float4 x2 = *(const float4*)(xt + (sn2*SS + s)*NIN);
        float4 x3 = *(const float4*)(xt + (sn3*SS + s)*NIN);
        float4 w0 = *(const float4*)(alpha + ((idx+0)*2 + s)*4);
        float4 w1 = *(const float4*)(alpha + ((idx+1)*2 + s)*4);
        float4 w2 = *(const float4*)(alpha + ((idx+2)*2 + s)*4);
        float4 w3 = *(const float4*)(alpha + ((idx+3)*2 + s)*4);
        float p, hd;
        p = c1h + x0.x*g1.x + x0.y*g1.y + x0.z*g1.z + x0.w*g1.w;
        hd = p + p2; hd = hd > 0.f ? hd : 0.f;
        a0 += w0.x*hd; a1 += w0.y*hd; a2 += w0.z*hd; a3 += w0.w*hd;
        p = c1h + x1.x*g1.x + x1.y*g1.y + x1.z*g1.z + x1.w*g1.w;
        hd = p + p2; hd = hd > 0.f ? hd : 0.f;
        a0 += w1.x*hd; a1 += w1.y*hd; a2 += w1.z*hd; a3 += w1.w*hd;
        p = c1h + x2.x*g1.x + x2.y*g1.y + x2.z*g1.z + x2.w*g1.w;
        hd = p + p2; hd = hd > 0.f ? hd : 0.f;
        a0 += w2.x*hd; a1 += w2.y*hd; a2 += w2.z*hd; a3 += w2.w*hd;
        p = c1h + x3.x*g1.x + x3.y*g1.y + x3.z*g1.z + x3.w*g1.w;
        hd = p + p2; hd = hd > 0.f ? hd : 0.f;
        a0 += w3.x*hd; a1 += w3.y*hd; a2 += w3.z*hd; a3 += w3.w*hd;
    }
    for (; idx < r1; ++idx) {
        int sn = src_by_pos[idx];
        float4 x0 = *(const float4*)(xt + (sn*SS + s)*NIN);
        float4 w0 = *(const float4*)(alpha + (idx*2 + s)*4);
        float p = c1h + x0.x*g1.x + x0.y*g1.y + x0.z*g1.z + x0.w*g1.w;
        float hd = p + p2; hd = hd > 0.f ? hd : 0.f;
        a0 += w0.x*hd; a1 += w0.y*hd; a2 += w0.z*hd; a3 += w0.w*hd;
    }
    agg_b[item*256 +       h] = f2b(a0);
    agg_b[item*256 + 64  + h] = f2b(a1);
    agg_b[item*256 + 128 + h] = f2b(a2);
    agg_b[item*256 + 192 + h] = f2b(a3);
}

// B3: GEMM0 (agg@W2^T block-diag per head) + chained node GEMMs.
// 4 waves/block, 16 items/wave. Per-wave LDS only, no barrier.
__global__ __launch_bounds__(256) void k_node_mfma(
    const unsigned short* __restrict__ agg_b, const unsigned short* __restrict__ zAb,
    const unsigned short* __restrict__ W2b,
    const unsigned short* __restrict__ F1w1b, const unsigned short* __restrict__ F1w2b,
    const unsigned short* __restrict__ ow1b, const unsigned short* __restrict__ ow2b,
    const float* __restrict__ ob1, const float* __restrict__ ob2,
    float* __restrict__ xt, float* __restrict__ out, int tstep)
{
    __shared__ unsigned short res_s[4][16*264];
    __shared__ unsigned short hid_s[4][16*72];
    __shared__ unsigned short hcat_s[4][16*104];
    int tid = threadIdx.x;
    int w = tid >> 6, l = tid & 63, l15 = l & 15, qq = l >> 4;

    bf16x8 w2f[2][4], b2f[2][4], o1f[3][4], bo2[2];
#pragma unroll
    for (int nb = 0; nb < 4; ++nb) {
        int n = nb*16 + l15;
#pragma unroll
        for (int kb = 0; kb < 2; ++kb) {
            w2f[kb][nb] = *(const bf16x8*)(W2b  + n*64 + kb*32 + qq*8);
            b2f[kb][nb] = *(const bf16x8*)(F1w2b + n*64 + kb*32 + qq*8);
        }
#pragma unroll
        for (int kb = 0; kb < 3; ++kb)
            o1f[kb][nb] = *(const bf16x8*)(ow1b + n*96 + kb*32 + qq*8);
    }
#pragma unroll
    for (int kb = 0; kb < 2; ++kb) {
        if (l15 < 4) bo2[kb] = *(const bf16x8*)(ow2b + l15*64 + kb*32 + qq*8);
        else {
            bf16x8 z;
#pragma unroll
            for (int j = 0; j < 8; ++j) z[j] = 0;
            bo2[kb] = z;
        }
    }
    float b1v[4];
#pragma unroll
    for (int nb = 0; nb < 4; ++nb) b1v[nb] = ob1[nb*16 + l15];
    float b2v = (l15 < 4) ? ob2[l15] : 0.0f;

    int itemBase = blockIdx.x*64 + w*16;
    if (itemBase >= NN*SS) return;

    *(uint4*)(&hcat_s[w][l15*104 + 64 + qq*8]) =
        *(const uint4*)(zAb + (itemBase + l15)*ZZ + qq*8);

    // GEMM0: res[item, k*64+h'] = sum_h agg[item,k*64+h] * W2[h'][h]
#pragma unroll
    for (int k = 0; k < 4; ++k) {
        f32x4 acc0[4];
#pragma unroll
        for (int nb = 0; nb < 4; ++nb) acc0[nb] = (f32x4)(0.0f);
#pragma unroll
        for (int kb = 0; kb < 2; ++kb) {
            bf16x8 af = *(const bf16x8*)(agg_b + (itemBase + l15)*256 + k*64 + kb*32 + qq*8);
#pragma unroll
            for (int nb = 0; nb < 4; ++nb)
                acc0[nb] = __builtin_amdgcn_mfma_f32_16x16x32_bf16(af, w2f[kb][nb], acc0[nb], 0, 0, 0);
        }
#pragma unroll
        for (int nb = 0; nb < 4; ++nb)
#pragma unroll
            for (int r = 0; r < 4; ++r)
                res_s[w][(qq*4 + r)*264 + k*64 + nb*16 + l15] = f2b(acc0[nb][r]);
    }

    // GEMM1: res[16x256] @ F1w1^T[256x64], relu
    f32x4 acc[4];
#pragma unroll
    for (int nb = 0; nb < 4; ++nb) acc[nb] = (f32x4)(0.0f);
#pragma unroll
    for (int kb = 0; kb < 8; ++kb) {
        bf16x8 af = *(const bf16x8*)(&res_s[w][l15*264 + kb*32 + qq*8]);
#pragma unroll
        for (int nb = 0; nb < 4; ++nb) {
            bf16x8 bf = *(const bf16x8*)(F1w1b + (nb*16 + l15)*256 + kb*32 + qq*8);
            acc[nb] = __builtin_amdgcn_mfma_f32_16x16x32_bf16(af, bf, acc[nb], 0, 0, 0);
        }
    }
#pragma unroll
    for (int nb = 0; nb < 4; ++nb)
#pragma unroll
        for (int r = 0; r < 4; ++r) {
            float v = acc[nb][r];
            hid_s[w][(qq*4 + r)*72 + nb*16 + l15] = f2b(v > 0.0f ? v : 0.0f);
        }

    // GEMM2: hid[16x64] @ F1w2^T[64x64] -> deltax -> hcat cols 0..63
    f32x4 acc2[4];
#pragma unroll
    for (int nb = 0; nb < 4; ++nb) acc2[nb] = (f32x4)(0.0f);
#pragma unroll
    for (int kb = 0; kb < 2; ++kb) {
        bf16x8 af = *(const bf16x8*)(&hid_s[w][l15*72 + kb*32 + qq*8]);
#pragma unroll
        for (int nb = 0; nb < 4; ++nb)
            acc2[nb] = __builtin_amdgcn_mfma_f32_16x16x32_bf16(af, b2f[kb][nb], acc2[nb], 0, 0, 0);
    }
#pragma unroll
    for (int nb = 0; nb < 4; ++nb)
#pragma unroll
        for (int r = 0; r < 4; ++r)
            hcat_s[w][(qq*4 + r)*104 + nb*16 + l15] = f2b(acc2[nb][r]);

    // GEMM3: hcat[16x96] @ ow1^T[96x64] + b1, relu -> hid_s
    f32x4 acc3[4];
#pragma unroll
    for (int nb = 0; nb < 4; ++nb) acc3[nb] = (f32x4)(0.0f);
#pragma unroll
    for (int kb = 0; kb < 3; ++kb) {
        bf16x8 af = *(const bf16x8*)(&hcat_s[w][l15*104 + kb*32 + qq*8]);
#pragma unroll
        for (int nb = 0; nb < 4; ++nb)
            acc3[nb] = __builtin_amdgcn_mfma_f32_16x16x32_bf16(af, o1f[kb][nb], acc3[nb], 0, 0, 0);
    }
#pragma unroll
    for (int nb = 0; nb < 4; ++nb)
#pragma unroll
        for (int r = 0; r < 4; ++r) {
            float v = acc3[nb][r] + b1v[nb];
            hid_s[w][(qq*4 + r)*72 + nb*16 + l15] = f2b(v > 0.0f ? v : 0.0f);
        }

    // GEMM4: hid[16x64] @ ow2^T[64x4(pad16)] + b2
    f32x4 acc4 = (f32x4)(0.0f);
#pragma unroll
    for (int kb = 0; kb < 2; ++kb) {
        bf16x8 af = *(const bf16x8*)(&hid_s[w][l15*72 + kb*32 + qq*8]);
        acc4 = __builtin_amdgcn_mfma_f32_16x16x32_bf16(af, bo2[kb], acc4, 0, 0, 0);
    }
    if (l15 < 4) {
#pragma unroll
        for (int r = 0; r < 4; ++r) {
            int item = itemBase + qq*4 + r;
            float nx = xt[item*4 + l15] + acc4[r] + b2v;
            xt[item*4 + l15] = nx;
            int n = item >> 1, s = item & 1;
            out[((n*TT + tstep)*SS + s)*4 + l15] = nx;
        }
    }
}

extern "C" void kernel_launch(void* const* d_in, const int* in_sizes, int n_in,
                              void* d_out, int out_size, void* d_ws, size_t ws_size,
                              hipStream_t stream) {
    const float* inputs = (const float*)d_in[0];
    const float* zA     = (const float*)d_in[1];
    const float* zG     = (const float*)d_in[2];
    const int*   src    = (const int*)d_in[3];
    const int*   dst    = (const int*)d_in[4];
    const float* Ws     = (const float*)d_in[5];
    const float* Wd     = (const float*)d_in[6];
    const float* F2w1   = (const float*)d_in[7];
    const float* F2w2   = (const float*)d_in[8];
    const float* F1w1   = (const float*)d_in[9];
    const float* F1w2   = (const float*)d_in[10];
    const float* xw     = (const float*)d_in[11];
    const float* xb     = (const float*)d_in[12];
    const float* ow1    = (const float*)d_in[13];
    const float* ob1    = (const float*)d_in[14];
    const float* ow2    = (const float*)d_in[15];
    const float* ob2    = (const float*)d_in[16];
    float* out = (float*)d_out;

    // ---- workspace carve (units: floats) ----
    float*          base        = (float*)d_ws;
    float*          MT          = base;                              // 4,096
    float*          alpha       = base + 4096;                       // 1,280,000
    int*            deg_i       = (int*)(base + 1284096);            // 10,000 (zeroed)
    int*            offsets     = (int*)(base + 1294096);            // 10,016
    int*            cursor      = (int*)(base + 1304112);            // 10,000
    int*            src_by_pos  = (int*)(base + 1314112);            // 160,000
    float*          xt          = base + 1474112;                    // 80,000
    float*          G1f         = base + 1554112;                    // 256
    float*          G2f         = base + 1554368;                    // 256
    float*          c1f         = base + 1554624;                    // 64
    float*          c2f         = base + 1554688;                    // 64 (pad to 1,554,816)
    unsigned short* W2b         = (unsigned short*)(base + 1554816); // 4,096 ush
    unsigned short* F1w1b       = (unsigned short*)(base + 1556864); // 16,384 ush
    unsigned short* F1w2b       = (unsigned short*)(base + 1565056); // 4,096 ush
    unsigned short* ow1b        = (unsigned short*)(base + 1567104); // 6,144 ush
    unsigned short* ow2b        = (unsigned short*)(base + 1570176); // 256 ush
    unsigned short* zAb         = (unsigned short*)(base + 1570304); // 640,000 ush
    unsigned short* zGb         = (unsigned short*)(base + 1890304); // 640,000 ush
    unsigned short* agg_b       = (unsigned short*)(base + 2210304); // 5,120,000 ush
    // total 4,770,304 floats = 19.1 MB

    hipMemsetAsync(deg_i, 0, 10000u * 4u, stream);

    // ---- attention phase (once) ----
    const int CONVB = (NN*SS*ZZ + 255)/256;   // 2500
    k_prep<<<17 + CONVB, 256, 0, stream>>>(Ws, Wd, F2w1, xw, xb, F2w2, F1w1, F1w2,
                                           ow1, ow2, zA, zG, inputs, dst,
                                           MT, G1f, G2f, c1f, c2f,
                                           W2b, F1w1b, F1w2b, ow1b, ow2b,
                                           zAb, zGb, xt, deg_i);
    k_scan<<<1, 1024, 0, stream>>>(deg_i, offsets, cursor);
    k_scatter<<<(NE + 255)/256, 256, 0, stream>>>(src, dst, cursor, src_by_pos);

    // ---- step 0 (attention fused with aggregation) ----
    k_attn_agg0<<<NN*SS, 64, 0, stream>>>(MT, zG, zGb, src_by_pos, offsets, xt,
                                          G1f, G2f, c1f, c2f, alpha, agg_b);
    k_node_mfma<<<(NN*SS + 63)/64, 256, 0, stream>>>(agg_b, zAb, W2b, F1w1b, F1w2b,
                                                     ow1b, ow2b, ob1, ob2, xt, out, 0);
    // ---- step 1 ----
    k_agg2<<<NN*SS, 64, 0, stream>>>(xt, G1f, G2f, c1f, c2f,
                                     src_by_pos, offsets, alpha, agg_b);
    k_node_mfma<<<(NN*SS + 63)/64, 256, 0, stream>>>(agg_b, zAb, W2b, F1w1b, F1w2b,
                                                     ow1b, ow2b, ob1, ob2, xt, out, 1);
}

// Round 7
// 223.215 us; speedup vs baseline: 1.1675x; 1.0157x over previous
//
#include <hip/hip_runtime.h>

#define NN 10000
#define NE 160000
#define TT 2
#define SS 2
#define HH 64
#define ZZ 32
#define KK 4
#define NIN 4

typedef short bf16x8 __attribute__((ext_vector_type(8)));
typedef float f32x4 __attribute__((ext_vector_type(4)));

// fp32 -> bf16 (RNE)
__device__ __forceinline__ unsigned short f2b(float x) {
    unsigned u = __float_as_uint(x);
    u += 0x7fffu + ((u >> 16) & 1u);
    return (unsigned short)(u >> 16);
}
__device__ __forceinline__ float bf2f(unsigned short u) {
    return __uint_as_float(((unsigned)u) << 16);
}

// wave-local LDS fence for single-wave blocks: wait DS ops only (NOT vmem),
// forbid compiler reordering.
__device__ __forceinline__ void wave_lds_fence() {
    asm volatile("s_waitcnt lgkmcnt(0)" ::: "memory");
    __builtin_amdgcn_wave_barrier();
}

// leaky(dot(zG_row(bf16 pairs), qf[32]))
__device__ __forceinline__ float edge_score(const unsigned* __restrict__ zp,
                                            const float* __restrict__ qf) {
    float a = 0.f;
#pragma unroll
    for (int j = 0; j < 16; ++j) {
        unsigned u = zp[j];
        a += __uint_as_float(u << 16) * qf[2*j]
           + __uint_as_float(u & 0xffff0000u) * qf[2*j+1];
    }
    return a > 0.f ? a : 0.01f*a;
}

// P0: merged prep. blocks 0..15: attnM (MT[k][j][i], transposed). block 16: fold.
// blocks 17+: bf16 conversions + xt init + deg count.
__global__ __launch_bounds__(256) void k_prep(
    const float* __restrict__ Ws, const float* __restrict__ Wd,
    const float* __restrict__ F2w1, const float* __restrict__ xw,
    const float* __restrict__ xb, const float* __restrict__ F2w2,
    const float* __restrict__ F1w1, const float* __restrict__ F1w2,
    const float* __restrict__ ow1, const float* __restrict__ ow2,
    const float* __restrict__ zA, const float* __restrict__ zG,
    const float* __restrict__ inputs, const int* __restrict__ dst,
    float* __restrict__ MT, float* __restrict__ G1, float* __restrict__ G2,
    float* __restrict__ c1, float* __restrict__ c2,
    unsigned short* __restrict__ W2b, unsigned short* __restrict__ F1w1b,
    unsigned short* __restrict__ F1w2b, unsigned short* __restrict__ ow1b,
    unsigned short* __restrict__ ow2b, unsigned short* __restrict__ zAb,
    unsigned short* __restrict__ zGb, float* __restrict__ xt,
    int* __restrict__ deg_i)
{
    int b = blockIdx.x;
    int tid = threadIdx.x;
    if (b < 16) {
        int o = b*256 + tid;              // 4096 outputs
        int j = o & 31, i = (o >> 5) & 31, k = o >> 10;
        float acc = 0.0f;
        for (int h = 0; h < HH; ++h)
            acc += Ws[(k*HH + h)*ZZ + i] * Wd[(k*HH + h)*ZZ + j];
        MT[(k*ZZ + j)*ZZ + i] = acc;
    } else if (b == 16) {
        int h = tid >> 2, i = tid & 3;
        float a1 = 0.f, a2 = 0.f;
        for (int j = 0; j < HH; ++j) {
            float x = xw[j*NIN + i];
            a1 += F2w1[h*128 + j] * x;
            a2 += F2w1[h*128 + 64 + j] * x;
        }
        G1[h*4 + i] = a1;
        G2[h*4 + i] = a2;
        if (i == 0) {
            float b1 = 0.f, b2 = 0.f;
            for (int j = 0; j < HH; ++j) {
                float bb = xb[j];
                b1 += F2w1[h*128 + j] * bb;
                b2 += F2w1[h*128 + 64 + j] * bb;
            }
            c1[h] = b1; c2[h] = b2;
        }
    } else {
        int t = (b - 17)*256 + tid;
        if (t < NN*SS*ZZ) { zAb[t] = f2b(zA[t]); zGb[t] = f2b(zG[t]); }
        if (t < HH*HH)    { W2b[t] = f2b(F2w2[t]); F1w2b[t] = f2b(F1w2[t]); }
        if (t < HH*KK*HH) F1w1b[t] = f2b(F1w1[t]);
        if (t < HH*(HH+ZZ)) ow1b[t] = f2b(ow1[t]);
        if (t < 4*HH)     ow2b[t] = f2b(ow2[t]);
        if (t < NN*SS*NIN) {
            int i = t & 3;
            int n = t >> 3;
            xt[t] = inputs[n*(TT*NIN) + i];
        }
        if (t < NE) atomicAdd(deg_i + dst[t], 1);
    }
}

// C2: exclusive scan of deg_i -> offsets[0..NN], cursor copy (1 block, Hillis-Steele)
__global__ void k_scan(const int* __restrict__ deg_i, int* __restrict__ offsets,
                       int* __restrict__ cursor) {
    __shared__ int buf0[1024], buf1[1024];
    int tidx = threadIdx.x;
    const int CH = (NN + 1023) / 1024;   // 10
    int b0 = tidx * CH;
    int sum = 0;
    for (int i = 0; i < CH; ++i) { int idx = b0 + i; if (idx < NN) sum += deg_i[idx]; }
    buf0[tidx] = sum;
    __syncthreads();
    int* s = buf0; int* d = buf1;
    for (int off = 1; off < 1024; off <<= 1) {
        d[tidx] = s[tidx] + (tidx >= off ? s[tidx - off] : 0);
        __syncthreads();
        int* tmp = s; s = d; d = tmp;
    }
    int run = s[tidx] - sum;
    for (int i = 0; i < CH; ++i) {
        int idx = b0 + i;
        if (idx < NN) { offsets[idx] = run; cursor[idx] = run; run += deg_i[idx]; }
    }
    if (tidx == 0) offsets[NN] = NE;
}

// C3: scatter src node ids into dst-sorted position order
__global__ void k_scatter(const int* __restrict__ src, const int* __restrict__ dst,
                          int* __restrict__ cursor, int* __restrict__ src_by_pos) {
    int e = blockIdx.x * blockDim.x + threadIdx.x;
    if (e >= NE) return;
    int pos = atomicAdd(cursor + dst[e], 1);
    src_by_pos[pos] = src[e];
}

// Fused attention + step-0 aggregation. ONE 64-thread block per NODE, TWO
// items per wave via lane-split: lanes 0-31 = (n,s=0), lanes 32-63 = (n,s=1).
// Same n in both halves -> identical deg -> no divergence between halves,
// single retire unit (no R1/R3/R5 coupling). The two items' dependent-load
// chains (phase 2: src_by_pos -> xt row -> FMA) execute in lockstep, doubling
// per-wave item throughput where the kernel is latency-bound; resident
// items/CU doubles at the fixed workgroup-slot cap.
// Per half: i = hl>>2 in [0,8) edges in flight, k = hl&3 heads. Reductions:
// 3 butterflies (off 4/8/16) stay within the half and preserve k.
// Phase 2: each lane handles h = hl and h+32.
__global__ __launch_bounds__(64) void k_attn_agg0(
    const float* __restrict__ MT, const float* __restrict__ zG,
    const unsigned short* __restrict__ zGb, const int* __restrict__ src_by_pos,
    const int* __restrict__ offsets, const float* __restrict__ xt,
    const float* __restrict__ G1, const float* __restrict__ G2,
    const float* __restrict__ c1, const float* __restrict__ c2,
    float* alpha, unsigned short* __restrict__ agg_b)
{
    __shared__ float sq[2][132];          // per-item qd [k*33+i] (+pad)
    __shared__ float alpha_s[2][64][4];   // per-item alpha cache, first 64 edges
    int n = blockIdx.x;
    int l = threadIdx.x;
    int half = l >> 5, hl = l & 31;
    int s = half;
    int item = n*2 + s;
    int i = hl >> 2, k = hl & 3;
    int r0 = offsets[n], r1 = offsets[n+1];
    int deg = r1 - r0;

    // ---- phase 0: qd in-half (4 entries per lane, i0 = hl) ----
    {
        const float* zg = zG + item*ZZ;
        float acc0 = 0.f, acc1 = 0.f, acc2 = 0.f, acc3 = 0.f;
#pragma unroll
        for (int j = 0; j < ZZ; ++j) {
            float z = zg[j];
            acc0 += MT[(0*ZZ + j)*ZZ + hl] * z;
            acc1 += MT[(1*ZZ + j)*ZZ + hl] * z;
            acc2 += MT[(2*ZZ + j)*ZZ + hl] * z;
            acc3 += MT[(3*ZZ + j)*ZZ + hl] * z;
        }
        sq[half][0*33 + hl] = acc0;
        sq[half][1*33 + hl] = acc1;
        sq[half][2*33 + hl] = acc2;
        sq[half][3*33 + hl] = acc3;
    }
    wave_lds_fence();
    float qf[32];
#pragma unroll
    for (int j = 0; j < 32; ++j) qf[j] = sq[half][k*33 + j];

    // ---- phase 1: scores -> alpha (8 edges in flight per item) ----
    float E[8];
    float mx = -1e30f;
    int nit = 0;
    for (int idx = r0 + i; idx < r1; idx += 8, ++nit) {
        int sn = src_by_pos[idx];
        float e = edge_score((const unsigned*)(zGb + (sn*SS + s)*ZZ), qf);
        if (nit < 8) E[nit] = e;
        mx = fmaxf(mx, e);
    }
#pragma unroll
    for (int off = 4; off < 32; off <<= 1) mx = fmaxf(mx, __shfl_xor(mx, off));
    float sum = 0.f;
    nit = 0;
    for (int idx = r0 + i; idx < r1; idx += 8, ++nit) {
        float e = (nit < 8) ? E[nit]
                : edge_score((const unsigned*)(zGb + (src_by_pos[idx]*SS + s)*ZZ), qf);
        float ex = __expf(e - mx);
        if (nit < 8) E[nit] = ex;      // cache exp for pass 3
        sum += ex;
    }
#pragma unroll
    for (int off = 4; off < 32; off <<= 1) sum += __shfl_xor(sum, off);
    float dd = (float)(deg > 1 ? deg : 1);
    float inv = sum > 0.f ? 1.f/(sum*dd) : 0.f;
    nit = 0;
    for (int idx = r0 + i; idx < r1; idx += 8, ++nit) {
        float a = ((nit < 8) ? E[nit]
                 : __expf(edge_score((const unsigned*)(zGb + (src_by_pos[idx]*SS + s)*ZZ), qf) - mx)) * inv;
        alpha[(idx*2 + s)*4 + k] = a;
        int jo = idx - r0;
        if (jo < 64) alpha_s[s][jo][k] = a;
    }
    wave_lds_fence();   // LDS-only dep; alpha global stores drain during phase 2

    // ---- phase 2: aggregation, each lane handles h = hl and h+32 ----
    int h = hl;
    const float4 g1a = *(const float4*)(G1 + h*4);
    const float4 g1b = *(const float4*)(G1 + (h+32)*4);
    const float4 g2a = *(const float4*)(G2 + h*4);
    const float4 g2b = *(const float4*)(G2 + (h+32)*4);
    const float4 xd = *(const float4*)(xt + item*4);
    float p2a = c2[h]    + xd.x*g2a.x + xd.y*g2a.y + xd.z*g2a.z + xd.w*g2a.w;
    float p2b = c2[h+32] + xd.x*g2b.x + xd.y*g2b.y + xd.z*g2b.z + xd.w*g2b.w;
    float c1a = c1[h], c1b = c1[h+32];
    float a0 = 0.f, a1 = 0.f, a2 = 0.f, a3 = 0.f;
    float b0 = 0.f, b1 = 0.f, b2 = 0.f, b3 = 0.f;
    int jo = 0;
    for (; jo + 4 <= deg; jo += 4) {
        int sn0 = src_by_pos[r0 + jo];
        int sn1 = src_by_pos[r0 + jo + 1];
        int sn2 = src_by_pos[r0 + jo + 2];
        int sn3 = src_by_pos[r0 + jo + 3];
        float4 x0 = *(const float4*)(xt + (sn0*SS + s)*NIN);
        float4 x1 = *(const float4*)(xt + (sn1*SS + s)*NIN);
        float4 x2 = *(const float4*)(xt + (sn2*SS + s)*NIN);
        float4 x3 = *(const float4*)(xt + (sn3*SS + s)*NIN);
        float4 w0 = (jo+0 < 64) ? *(const float4*)(&alpha_s[s][jo+0][0])
                                : *(const float4*)(alpha + ((r0+jo+0)*2 + s)*4);
        float4 w1 = (jo+1 < 64) ? *(const float4*)(&alpha_s[s][jo+1][0])
                                : *(const float4*)(alpha + ((r0+jo+1)*2 + s)*4);
        float4 w2 = (jo+2 < 64) ? *(const float4*)(&alpha_s[s][jo+2][0])
                                : *(const float4*)(alpha + ((r0+jo+2)*2 + s)*4);
        float4 w3 = (jo+3 < 64) ? *(const float4*)(&alpha_s[s][jo+3][0])
                                : *(const float4*)(alpha + ((r0+jo+3)*2 + s)*4);
        float pa, pb, hda, hdb;
        pa = c1a + x0.x*g1a.x + x0.y*g1a.y + x0.z*g1a.z + x0.w*g1a.w;
        pb = c1b + x0.x*g1b.x + x0.y*g1b.y + x0.z*g1b.z + x0.w*g1b.w;
        hda = pa + p2a; hda = hda > 0.f ? hda : 0.f;
        hdb = pb + p2b; hdb = hdb > 0.f ? hdb : 0.f;
        a0 += w0.x*hda; a1 += w0.y*hda; a2 += w0.z*hda; a3 += w0.w*hda;
        b0 += w0.x*hdb; b1 += w0.y*hdb; b2 += w0.z*hdb; b3 += w0.w*hdb;
        pa = c1a + x1.x*g1a.x + x1.y*g1a.y + x1.z*g1a.z + x1.w*g1a.w;
        pb = c1b + x1.x*g1b.x + x1.y*g1b.y + x1.z*g1b.z + x1.w*g1b.w;
        hda = pa + p2a; hda = hda > 0.f ? hda : 0.f;
        hdb = pb + p2b; hdb = hdb > 0.f ? hdb : 0.f;
        a0 += w1.x*hda; a1 += w1.y*hda; a2 += w1.z*hda; a3 += w1.w*hda;
        b0 += w1.x*hdb; b1 += w1.y*hdb; b2 += w1.z*hdb; b3 += w1.w*hdb;
        pa = c1a + x2.x*g1a.x + x2.y*g1a.y + x2.z*g1a.z + x2.w*g1a.w;
        pb = c1b + x2.x*g1b.x + x2.y*g1b.y + x2.z*g1b.z + x2.w*g1b.w;
        hda = pa + p2a; hda = hda > 0.f ? hda : 0.f;
        hdb = pb + p2b; hdb = hdb > 0.f ? hdb : 0.f;
        a0 += w2.x*hda; a1 += w2.y*hda; a2 += w2.z*hda; a3 += w2.w*hda;
        b0 += w2.x*hdb; b1 += w2.y*hdb; b2 += w2.z*hdb; b3 += w2.w*hdb;
        pa = c1a + x3.x*g1a.x + x3.y*g1a.y + x3.z*g1a.z + x3.w*g1a.w;
        pb = c1b + x3.x*g1b.x + x3.y*g1b.y + x3.z*g1b.z + x3.w*g1b.w;
        hda = pa + p2a; hda = hda > 0.f ? hda : 0.f;
        hdb = pb + p2b; hdb = hdb > 0.f ? hdb : 0.f;
        a0 += w3.x*hda; a1 += w3.y*hda; a2 += w3.z*hda; a3 += w3.w*hda;
        b0 += w3.x*hdb; b1 += w3.y*hdb; b2 += w3.z*hdb; b3 += w3.w*hdb;
    }
    for (; jo < deg; ++jo) {
        int sn = src_by_pos[r0 + jo];
        float4 x0 = *(const float4*)(xt + (sn*SS + s)*NIN);
        float4 w4 = (jo < 64) ? *(const float4*)(&alpha_s[s][jo][0])
                              : *(const float4*)(alpha + ((r0+jo)*2 + s)*4);
        float pa = c1a + x0.x*g1a.x + x0.y*g1a.y + x0.z*g1a.z + x0.w*g1a.w;
        float pb = c1b + x0.x*g1b.x + x0.y*g1b.y + x0.z*g1b.z + x0.w*g1b.w;
        float hda = pa + p2a; hda = hda > 0.f ? hda : 0.f;
        float hdb = pb + p2b; hdb = hdb > 0.f ? hdb : 0.f;
        a0 += w4.x*hda; a1 += w4.y*hda; a2 += w4.z*hda; a3 += w4.w*hda;
        b0 += w4.x*hdb; b1 += w4.y*hdb; b2 += w4.z*hdb; b3 += w4.w*hdb;
    }
    agg_b[item*256 +       h] = f2b(a0);
    agg_b[item*256 + 64  + h] = f2b(a1);
    agg_b[item*256 + 128 + h] = f2b(a2);
    agg_b[item*256 + 192 + h] = f2b(a3);
    agg_b[item*256 +       h+32] = f2b(b0);
    agg_b[item*256 + 64  + h+32] = f2b(b1);
    agg_b[item*256 + 128 + h+32] = f2b(b2);
    agg_b[item*256 + 192 + h+32] = f2b(b3);
}

// B2: fused xenc + edge layer-1 + aggregation (step 1). Same 2-items-per-wave
// lane-split as attn: lanes 0-31 = (n,0), lanes 32-63 = (n,1); each lane
// handles h = hl and h+32.
__global__ __launch_bounds__(64) void k_agg2(
    const float* __restrict__ xt, const float* __restrict__ G1,
    const float* __restrict__ G2, const float* __restrict__ c1,
    const float* __restrict__ c2, const int* __restrict__ src_by_pos,
    const int* __restrict__ offsets, const float* __restrict__ alpha,
    unsigned short* __restrict__ agg_b)
{
    int n = blockIdx.x;
    int l = threadIdx.x;
    int half = l >> 5, hl = l & 31;
    int s = half;
    int item = n*2 + s;
    int r0 = offsets[n], r1 = offsets[n+1];
    int h = hl;
    const float4 g1a = *(const float4*)(G1 + h*4);
    const float4 g1b = *(const float4*)(G1 + (h+32)*4);
    const float4 g2a = *(const float4*)(G2 + h*4);
    const float4 g2b = *(const float4*)(G2 + (h+32)*4);
    const float4 xd = *(const float4*)(xt + item*4);
    float p2a = c2[h]    + xd.x*g2a.x + xd.y*g2a.y + xd.z*g2a.z + xd.w*g2a.w;
    float p2b = c2[h+32] + xd.x*g2b.x + xd.y*g2b.y + xd.z*g2b.z + xd.w*g2b.w;
    float c1a = c1[h], c1b = c1[h+32];
    float a0 = 0.f, a1 = 0.f, a2 = 0.f, a3 = 0.f;
    float b0 = 0.f, b1 = 0.f, b2 = 0.f, b3 = 0.f;
    int idx = r0;
    for (; idx + 4 <= r1; idx += 4) {
        int sn0 = src_by_pos[idx];
        int sn1 = src_by_pos[idx+1];
        int sn2 = src_by_pos[idx+2];
        int sn3 = src_by_pos[idx+3];
        float4 x0 = *(const float4*)(xt + (sn0*SS + s)*NIN);
        float4 x1 = *(const float4*)(xt + (sn1*SS + s)*NIN);
        float4 x2 = *(const float4*)(xt + (sn2*SS + s)*NIN);
        float4 x3 = *(const float4*)(xt + (sn3*SS + s)*NIN);
        float4 w0 = *(const float4*)(alpha + ((idx+0)*2 + s)*4);
        float4 w1 = *(const float4*)(alpha + ((idx+1)*2 + s)*4);
        float4 w2 = *(const float4*)(alpha + ((idx+2)*2 + s)*4);
        float4 w3 = *(const float4*)(alpha + ((idx+3)*2 + s)*4);
        float pa, pb, hda, hdb;
        pa = c1a + x0.x*g1a.x + x0.y*g1a.y + x0.z*g1a.z + x0.w*g1a.w;
        pb = c1b + x0.x*g1b.x + x0.y*g1b.y + x0.z*g1b.z + x0.w*g1b.w;
        hda = pa + p2a; hda = hda > 0.f ? hda : 0.f;
        hdb = pb + p2b; hdb = hdb > 0.f ? hdb : 0.f;
        a0 += w0.x*hda; a1 += w0.y*hda; a2 += w0.z*hda; a3 += w0.w*hda;
        b0 += w0.x*hdb; b1 += w0.y*hdb; b2 += w0.z*hdb; b3 += w0.w*hdb;
        pa = c1a + x1.x*g1a.x + x1.y*g1a.y + x1.z*g1a.z + x1.w*g1a.w;
        pb = c1b + x1.x*g1b.x + x1.y*g1b.y + x1.z*g1b.z + x1.w*g1b.w;
        hda = pa + p2a; hda = hda > 0.f ? hda : 0.f;
        hdb = pb + p2b; hdb = hdb > 0.f ? hdb : 0.f;
        a0 += w1.x*hda; a1 += w1.y*hda; a2 += w1.z*hda; a3 += w1.w*hda;
        b0 += w1.x*hdb; b1 += w1.y*hdb; b2 += w1.z*hdb; b3 += w1.w*hdb;
        pa = c1a + x2.x*g1a.x + x2.y*g1a.y + x2.z*g1a.z + x2.w*g1a.w;
        pb = c1b + x2.x*g1b.x + x2.y*g1b.y + x2.z*g1b.z + x2.w*g1b.w;
        hda = pa + p2a; hda = hda > 0.f ? hda : 0.f;
        hdb = pb + p2b; hdb = hdb > 0.f ? hdb : 0.f;
        a0 += w2.x*hda; a1 += w2.y*hda; a2 += w2.z*hda; a3 += w2.w*hda;
        b0 += w2.x*hdb; b1 += w2.y*hdb; b2 += w2.z*hdb; b3 += w2.w*hdb;
        pa = c1a + x3.x*g1a.x + x3.y*g1a.y + x3.z*g1a.z + x3.w*g1a.w;
        pb = c1b + x3.x*g1b.x + x3.y*g1b.y + x3.z*g1b.z + x3.w*g1b.w;
        hda = pa + p2a; hda = hda > 0.f ? hda : 0.f;
        hdb = pb + p2b; hdb = hdb > 0.f ? hdb : 0.f;
        a0 += w3.x*hda; a1 += w3.y*hda; a2 += w3.z*hda; a3 += w3.w*hda;
        b0 += w3.x*hdb; b1 += w3.y*hdb; b2 += w3.z*hdb; b3 += w3.w*hdb;
    }
    for (; idx < r1; ++idx) {
        int sn = src_by_pos[idx];
        float4 x0 = *(const float4*)(xt + (sn*SS + s)*NIN);
        float4 w0 = *(const float4*)(alpha + (idx*2 + s)*4);
        float pa = c1a + x0.x*g1a.x + x0.y*g1a.y + x0.z*g1a.z + x0.w*g1a.w;
        float pb = c1b + x0.x*g1b.x + x0.y*g1b.y + x0.z*g1b.z + x0.w*g1b.w;
        float hda = pa + p2a; hda = hda > 0.f ? hda : 0.f;
        float hdb = pb + p2b; hdb = hdb > 0.f ? hdb : 0.f;
        a0 += w0.x*hda; a1 += w0.y*hda; a2 += w0.z*hda; a3 += w0.w*hda;
        b0 += w0.x*hdb; b1 += w0.y*hdb; b2 += w0.z*hdb; b3 += w0.w*hdb;
    }
    agg_b[item*256 +       h] = f2b(a0);
    agg_b[item*256 + 64  + h] = f2b(a1);
    agg_b[item*256 + 128 + h] = f2b(a2);
    agg_b[item*256 + 192 + h] = f2b(a3);
    agg_b[item*256 +       h+32] = f2b(b0);
    agg_b[item*256 + 64  + h+32] = f2b(b1);
    agg_b[item*256 + 128 + h+32] = f2b(b2);
    agg_b[item*256 + 192 + h+32] = f2b(b3);
}

// B3: GEMM0 (agg@W2^T block-diag per head) + chained node GEMMs.
// 4 waves/block, 16 items/wave. Per-wave LDS only, no barrier.
__global__ __launch_bounds__(256) void k_node_mfma(
    const unsigned short* __restrict__ agg_b, const unsigned short* __restrict__ zAb,
    const unsigned short* __restrict__ W2b,
    const unsigned short* __restrict__ F1w1b, const unsigned short* __restrict__ F1w2b,
    const unsigned short* __restrict__ ow1b, const unsigned short* __restrict__ ow2b,
    const float* __restrict__ ob1, const float* __restrict__ ob2,
    float* __restrict__ xt, float* __restrict__ out, int tstep)
{
    __shared__ unsigned short res_s[4][16*264];
    __shared__ unsigned short hid_s[4][16*72];
    __shared__ unsigned short hcat_s[4][16*104];
    int tid = threadIdx.x;
    int w = tid >> 6, l = tid & 63, l15 = l & 15, qq = l >> 4;

    bf16x8 w2f[2][4], b2f[2][4], o1f[3][4], bo2[2];
#pragma unroll
    for (int nb = 0; nb < 4; ++nb) {
        int n = nb*16 + l15;
#pragma unroll
        for (int kb = 0; kb < 2; ++kb) {
            w2f[kb][nb] = *(const bf16x8*)(W2b  + n*64 + kb*32 + qq*8);
            b2f[kb][nb] = *(const bf16x8*)(F1w2b + n*64 + kb*32 + qq*8);
        }
#pragma unroll
        for (int kb = 0; kb < 3; ++kb)
            o1f[kb][nb] = *(const bf16x8*)(ow1b + n*96 + kb*32 + qq*8);
    }
#pragma unroll
    for (int kb = 0; kb < 2; ++kb) {
        if (l15 < 4) bo2[kb] = *(const bf16x8*)(ow2b + l15*64 + kb*32 + qq*8);
        else {
            bf16x8 z;
#pragma unroll
            for (int j = 0; j < 8; ++j) z[j] = 0;
            bo2[kb] = z;
        }
    }
    float b1v[4];
#pragma unroll
    for (int nb = 0; nb < 4; ++nb) b1v[nb] = ob1[nb*16 + l15];
    float b2v = (l15 < 4) ? ob2[l15] : 0.0f;

    int itemBase = blockIdx.x*64 + w*16;
    if (itemBase >= NN*SS) return;

    *(uint4*)(&hcat_s[w][l15*104 + 64 + qq*8]) =
        *(const uint4*)(zAb + (itemBase + l15)*ZZ + qq*8);

    // GEMM0: res[item, k*64+h'] = sum_h agg[item,k*64+h] * W2[h'][h]
#pragma unroll
    for (int k = 0; k < 4; ++k) {
        f32x4 acc0[4];
#pragma unroll
        for (int nb = 0; nb < 4; ++nb) acc0[nb] = (f32x4)(0.0f);
#pragma unroll
        for (int kb = 0; kb < 2; ++kb) {
            bf16x8 af = *(const bf16x8*)(agg_b + (itemBase + l15)*256 + k*64 + kb*32 + qq*8);
#pragma unroll
            for (int nb = 0; nb < 4; ++nb)
                acc0[nb] = __builtin_amdgcn_mfma_f32_16x16x32_bf16(af, w2f[kb][nb], acc0[nb], 0, 0, 0);
        }
#pragma unroll
        for (int nb = 0; nb < 4; ++nb)
#pragma unroll
            for (int r = 0; r < 4; ++r)
                res_s[w][(qq*4 + r)*264 + k*64 + nb*16 + l15] = f2b(acc0[nb][r]);
    }

    // GEMM1: res[16x256] @ F1w1^T[256x64], relu
    f32x4 acc[4];
#pragma unroll
    for (int nb = 0; nb < 4; ++nb) acc[nb] = (f32x4)(0.0f);
#pragma unroll
    for (int kb = 0; kb < 8; ++kb) {
        bf16x8 af = *(const bf16x8*)(&res_s[w][l15*264 + kb*32 + qq*8]);
#pragma unroll
        for (int nb = 0; nb < 4; ++nb) {
            bf16x8 bf = *(const bf16x8*)(F1w1b + (nb*16 + l15)*256 + kb*32 + qq*8);
            acc[nb] = __builtin_amdgcn_mfma_f32_16x16x32_bf16(af, bf, acc[nb], 0, 0, 0);
        }
    }
#pragma unroll
    for (int nb = 0; nb < 4; ++nb)
#pragma unroll
        for (int r = 0; r < 4; ++r) {
            float v = acc[nb][r];
            hid_s[w][(qq*4 + r)*72 + nb*16 + l15] = f2b(v > 0.0f ? v : 0.0f);
        }

    // GEMM2: hid[16x64] @ F1w2^T[64x64] -> deltax -> hcat cols 0..63
    f32x4 acc2[4];
#pragma unroll
    for (int nb = 0; nb < 4; ++nb) acc2[nb] = (f32x4)(0.0f);
#pragma unroll
    for (int kb = 0; kb < 2; ++kb) {
        bf16x8 af = *(const bf16x8*)(&hid_s[w][l15*72 + kb*32 + qq*8]);
#pragma unroll
        for (int nb = 0; nb < 4; ++nb)
            acc2[nb] = __builtin_amdgcn_mfma_f32_16x16x32_bf16(af, b2f[kb][nb], acc2[nb], 0, 0, 0);
    }
#pragma unroll
    for (int nb = 0; nb < 4; ++nb)
#pragma unroll
        for (int r = 0; r < 4; ++r)
            hcat_s[w][(qq*4 + r)*104 + nb*16 + l15] = f2b(acc2[nb][r]);

    // GEMM3: hcat[16x96] @ ow1^T[96x64] + b1, relu -> hid_s
    f32x4 acc3[4];
#pragma unroll
    for (int nb = 0; nb < 4; ++nb) acc3[nb] = (f32x4)(0.0f);
#pragma unroll
    for (int kb = 0; kb < 3; ++kb) {
        bf16x8 af = *(const bf16x8*)(&hcat_s[w][l15*104 + kb*32 + qq*8]);
#pragma unroll
        for (int nb = 0; nb < 4; ++nb)
            acc3[nb] = __builtin_amdgcn_mfma_f32_16x16x32_bf16(af, o1f[kb][nb], acc3[nb], 0, 0, 0);
    }
#pragma unroll
    for (int nb = 0; nb < 4; ++nb)
#pragma unroll
        for (int r = 0; r < 4; ++r) {
            float v = acc3[nb][r] + b1v[nb];
            hid_s[w][(qq*4 + r)*72 + nb*16 + l15] = f2b(v > 0.0f ? v : 0.0f);
        }

    // GEMM4: hid[16x64] @ ow2^T[64x4(pad16)] + b2
    f32x4 acc4 = (f32x4)(0.0f);
#pragma unroll
    for (int kb = 0; kb < 2; ++kb) {
        bf16x8 af = *(const bf16x8*)(&hid_s[w][l15*72 + kb*32 + qq*8]);
        acc4 = __builtin_amdgcn_mfma_f32_16x16x32_bf16(af, bo2[kb], acc4, 0, 0, 0);
    }
    if (l15 < 4) {
#pragma unroll
        for (int r = 0; r < 4; ++r) {
            int item = itemBase + qq*4 + r;
            float nx = xt[item*4 + l15] + acc4[r] + b2v;
            xt[item*4 + l15] = nx;
            int n = item >> 1, s = item & 1;
            out[((n*TT + tstep)*SS + s)*4 + l15] = nx;
        }
    }
}

extern "C" void kernel_launch(void* const* d_in, const int* in_sizes, int n_in,
                              void* d_out, int out_size, void* d_ws, size_t ws_size,
                              hipStream_t stream) {
    const float* inputs = (const float*)d_in[0];
    const float* zA     = (const float*)d_in[1];
    const float* zG     = (const float*)d_in[2];
    const int*   src    = (const int*)d_in[3];
    const int*   dst    = (const int*)d_in[4];
    const float* Ws     = (const float*)d_in[5];
    const float* Wd     = (const float*)d_in[6];
    const float* F2w1   = (const float*)d_in[7];
    const float* F2w2   = (const float*)d_in[8];
    const float* F1w1   = (const float*)d_in[9];
    const float* F1w2   = (const float*)d_in[10];
    const float* xw     = (const float*)d_in[11];
    const float* xb     = (const float*)d_in[12];
    const float* ow1    = (const float*)d_in[13];
    const float* ob1    = (const float*)d_in[14];
    const float* ow2    = (const float*)d_in[15];
    const float* ob2    = (const float*)d_in[16];
    float* out = (float*)d_out;

    // ---- workspace carve (units: floats) ----
    float*          base        = (float*)d_ws;
    float*          MT          = base;                              // 4,096
    float*          alpha       = base + 4096;                       // 1,280,000
    int*            deg_i       = (int*)(base + 1284096);            // 10,000 (zeroed)
    int*            offsets     = (int*)(base + 1294096);            // 10,016
    int*            cursor      = (int*)(base + 1304112);            // 10,000
    int*            src_by_pos  = (int*)(base + 1314112);            // 160,000
    float*          xt          = base + 1474112;                    // 80,000
    float*          G1f         = base + 1554112;                    // 256
    float*          G2f         = base + 1554368;                    // 256
    float*          c1f         = base + 1554624;                    // 64
    float*          c2f         = base + 1554688;                    // 64 (pad to 1,554,816)
    unsigned short* W2b         = (unsigned short*)(base + 1554816); // 4,096 ush
    unsigned short* F1w1b       = (unsigned short*)(base + 1556864); // 16,384 ush
    unsigned short* F1w2b       = (unsigned short*)(base + 1565056); // 4,096 ush
    unsigned short* ow1b        = (unsigned short*)(base + 1567104); // 6,144 ush
    unsigned short* ow2b        = (unsigned short*)(base + 1570176); // 256 ush
    unsigned short* zAb         = (unsigned short*)(base + 1570304); // 640,000 ush
    unsigned short* zGb         = (unsigned short*)(base + 1890304); // 640,000 ush
    unsigned short* agg_b       = (unsigned short*)(base + 2210304); // 5,120,000 ush
    // total 4,770,304 floats = 19.1 MB

    hipMemsetAsync(deg_i, 0, 10000u * 4u, stream);

    // ---- attention phase (once) ----
    const int CONVB = (NN*SS*ZZ + 255)/256;   // 2500
    k_prep<<<17 + CONVB, 256, 0, stream>>>(Ws, Wd, F2w1, xw, xb, F2w2, F1w1, F1w2,
                                           ow1, ow2, zA, zG, inputs, dst,
                                           MT, G1f, G2f, c1f, c2f,
                                           W2b, F1w1b, F1w2b, ow1b, ow2b,
                                           zAb, zGb, xt, deg_i);
    k_scan<<<1, 1024, 0, stream>>>(deg_i, offsets, cursor);
    k_scatter<<<(NE + 255)/256, 256, 0, stream>>>(src, dst, cursor, src_by_pos);

    // ---- step 0 (attention fused with aggregation) ----
    k_attn_agg0<<<NN, 64, 0, stream>>>(MT, zG, zGb, src_by_pos, offsets, xt,
                                       G1f, G2f, c1f, c2f, alpha, agg_b);
    k_node_mfma<<<(NN*SS + 63)/64, 256, 0, stream>>>(agg_b, zAb, W2b, F1w1b, F1w2b,
                                                     ow1b, ow2b, ob1, ob2, xt, out, 0);
    // ---- step 1 ----
    k_agg2<<<NN, 64, 0, stream>>>(xt, G1f, G2f, c1f, c2f,
                                  src_by_pos, offsets, alpha, agg_b);
    k_node_mfma<<<(NN*SS + 63)/64, 256, 0, stream>>>(agg_b, zAb, W2b, F1w1b, F1w2b,
                                                     ow1b, ow2b, ob1, ob2, xt, out, 1);
}

// Round 8
// 220.316 us; speedup vs baseline: 1.1829x; 1.0132x over previous
//
#include <hip/hip_runtime.h>

#define NN 10000
#define NE 160000
#define TT 2
#define SS 2
#define HH 64
#define ZZ 32
#define KK 4
#define NIN 4

typedef short bf16x8 __attribute__((ext_vector_type(8)));
typedef float f32x4 __attribute__((ext_vector_type(4)));

// fp32 -> bf16 (RNE)
__device__ __forceinline__ unsigned short f2b(float x) {
    unsigned u = __float_as_uint(x);
    u += 0x7fffu + ((u >> 16) & 1u);
    return (unsigned short)(u >> 16);
}
__device__ __forceinline__ float bf2f(unsigned short u) {
    return __uint_as_float(((unsigned)u) << 16);
}

// wave-local LDS fence for single-wave blocks: wait DS ops only (NOT vmem),
// forbid compiler reordering.
__device__ __forceinline__ void wave_lds_fence() {
    asm volatile("s_waitcnt lgkmcnt(0)" ::: "memory");
    __builtin_amdgcn_wave_barrier();
}

// leaky(dot(zG_row(bf16 pairs), qf[32])), 4 independent accumulators:
// chain depth 8 instead of 32 (R7 post-mortem: kernel is FMA-chain
// latency-bound; 4-way ILP cuts exposed latency ~3x per score).
__device__ __forceinline__ float edge_score(const unsigned* __restrict__ zp,
                                            const float* __restrict__ qf) {
    float a0 = 0.f, a1 = 0.f, a2 = 0.f, a3 = 0.f;
#pragma unroll
    for (int j = 0; j < 16; j += 4) {
        unsigned u0 = zp[j+0], u1 = zp[j+1], u2 = zp[j+2], u3 = zp[j+3];
        a0 += __uint_as_float(u0 << 16)         * qf[2*j+0]
            + __uint_as_float(u0 & 0xffff0000u) * qf[2*j+1];
        a1 += __uint_as_float(u1 << 16)         * qf[2*j+2]
            + __uint_as_float(u1 & 0xffff0000u) * qf[2*j+3];
        a2 += __uint_as_float(u2 << 16)         * qf[2*j+4]
            + __uint_as_float(u2 & 0xffff0000u) * qf[2*j+5];
        a3 += __uint_as_float(u3 << 16)         * qf[2*j+6]
            + __uint_as_float(u3 & 0xffff0000u) * qf[2*j+7];
    }
    float a = (a0 + a1) + (a2 + a3);
    return a > 0.f ? a : 0.01f*a;
}

// P0: merged prep. blocks 0..15: attnM (MT[k][j][i], transposed). block 16: fold.
// blocks 17+: bf16 conversions + xt init + deg count.
__global__ __launch_bounds__(256) void k_prep(
    const float* __restrict__ Ws, const float* __restrict__ Wd,
    const float* __restrict__ F2w1, const float* __restrict__ xw,
    const float* __restrict__ xb, const float* __restrict__ F2w2,
    const float* __restrict__ F1w1, const float* __restrict__ F1w2,
    const float* __restrict__ ow1, const float* __restrict__ ow2,
    const float* __restrict__ zA, const float* __restrict__ zG,
    const float* __restrict__ inputs, const int* __restrict__ dst,
    float* __restrict__ MT, float* __restrict__ G1, float* __restrict__ G2,
    float* __restrict__ c1, float* __restrict__ c2,
    unsigned short* __restrict__ W2b, unsigned short* __restrict__ F1w1b,
    unsigned short* __restrict__ F1w2b, unsigned short* __restrict__ ow1b,
    unsigned short* __restrict__ ow2b, unsigned short* __restrict__ zAb,
    unsigned short* __restrict__ zGb, float* __restrict__ xt,
    int* __restrict__ deg_i)
{
    int b = blockIdx.x;
    int tid = threadIdx.x;
    if (b < 16) {
        int o = b*256 + tid;              // 4096 outputs
        int j = o & 31, i = (o >> 5) & 31, k = o >> 10;
        float acc = 0.0f;
        for (int h = 0; h < HH; ++h)
            acc += Ws[(k*HH + h)*ZZ + i] * Wd[(k*HH + h)*ZZ + j];
        MT[(k*ZZ + j)*ZZ + i] = acc;
    } else if (b == 16) {
        int h = tid >> 2, i = tid & 3;
        float a1 = 0.f, a2 = 0.f;
        for (int j = 0; j < HH; ++j) {
            float x = xw[j*NIN + i];
            a1 += F2w1[h*128 + j] * x;
            a2 += F2w1[h*128 + 64 + j] * x;
        }
        G1[h*4 + i] = a1;
        G2[h*4 + i] = a2;
        if (i == 0) {
            float b1 = 0.f, b2 = 0.f;
            for (int j = 0; j < HH; ++j) {
                float bb = xb[j];
                b1 += F2w1[h*128 + j] * bb;
                b2 += F2w1[h*128 + 64 + j] * bb;
            }
            c1[h] = b1; c2[h] = b2;
        }
    } else {
        int t = (b - 17)*256 + tid;
        if (t < NN*SS*ZZ) { zAb[t] = f2b(zA[t]); zGb[t] = f2b(zG[t]); }
        if (t < HH*HH)    { W2b[t] = f2b(F2w2[t]); F1w2b[t] = f2b(F1w2[t]); }
        if (t < HH*KK*HH) F1w1b[t] = f2b(F1w1[t]);
        if (t < HH*(HH+ZZ)) ow1b[t] = f2b(ow1[t]);
        if (t < 4*HH)     ow2b[t] = f2b(ow2[t]);
        if (t < NN*SS*NIN) {
            int i = t & 3;
            int n = t >> 3;
            xt[t] = inputs[n*(TT*NIN) + i];
        }
        if (t < NE) atomicAdd(deg_i + dst[t], 1);
    }
}

// C2: exclusive scan of deg_i -> offsets[0..NN], cursor copy (1 block, Hillis-Steele)
__global__ void k_scan(const int* __restrict__ deg_i, int* __restrict__ offsets,
                       int* __restrict__ cursor) {
    __shared__ int buf0[1024], buf1[1024];
    int tidx = threadIdx.x;
    const int CH = (NN + 1023) / 1024;   // 10
    int b0 = tidx * CH;
    int sum = 0;
    for (int i = 0; i < CH; ++i) { int idx = b0 + i; if (idx < NN) sum += deg_i[idx]; }
    buf0[tidx] = sum;
    __syncthreads();
    int* s = buf0; int* d = buf1;
    for (int off = 1; off < 1024; off <<= 1) {
        d[tidx] = s[tidx] + (tidx >= off ? s[tidx - off] : 0);
        __syncthreads();
        int* tmp = s; s = d; d = tmp;
    }
    int run = s[tidx] - sum;
    for (int i = 0; i < CH; ++i) {
        int idx = b0 + i;
        if (idx < NN) { offsets[idx] = run; cursor[idx] = run; run += deg_i[idx]; }
    }
    if (tidx == 0) offsets[NN] = NE;
}

// C3: scatter src node ids into dst-sorted position order
__global__ void k_scatter(const int* __restrict__ src, const int* __restrict__ dst,
                          int* __restrict__ cursor, int* __restrict__ src_by_pos) {
    int e = blockIdx.x * blockDim.x + threadIdx.x;
    if (e >= NE) return;
    int pos = atomicAdd(cursor + dst[e], 1);
    src_by_pos[pos] = src[e];
}

// Fused attention + step-0 aggregation. ONE 64-thread block per NODE, TWO
// items per wave via lane-split (R7 geometry — best measured).
// Softmax without the max pass: alpha = exp(min(e,80))/sum is mathematically
// identical to max-subtracted softmax (ratio invariance); scores are
// ~N(0,8) so the clamp never binds in practice, and even fully-clamped sums
// (deg*e^80) cannot overflow fp32. Removes one butterfly reduction and one
// pass over the edges from the per-item critical path.
__global__ __launch_bounds__(64) void k_attn_agg0(
    const float* __restrict__ MT, const float* __restrict__ zG,
    const unsigned short* __restrict__ zGb, const int* __restrict__ src_by_pos,
    const int* __restrict__ offsets, const float* __restrict__ xt,
    const float* __restrict__ G1, const float* __restrict__ G2,
    const float* __restrict__ c1, const float* __restrict__ c2,
    float* alpha, unsigned short* __restrict__ agg_b)
{
    __shared__ float sq[2][132];          // per-item qd [k*33+i] (+pad)
    __shared__ float alpha_s[2][64][4];   // per-item alpha cache, first 64 edges
    int n = blockIdx.x;
    int l = threadIdx.x;
    int half = l >> 5, hl = l & 31;
    int s = half;
    int item = n*2 + s;
    int i = hl >> 2, k = hl & 3;
    int r0 = offsets[n], r1 = offsets[n+1];
    int deg = r1 - r0;

    // ---- phase 0: qd in-half (4 entries per lane, i0 = hl) ----
    {
        const float* zg = zG + item*ZZ;
        float acc0 = 0.f, acc1 = 0.f, acc2 = 0.f, acc3 = 0.f;
#pragma unroll
        for (int j = 0; j < ZZ; ++j) {
            float z = zg[j];
            acc0 += MT[(0*ZZ + j)*ZZ + hl] * z;
            acc1 += MT[(1*ZZ + j)*ZZ + hl] * z;
            acc2 += MT[(2*ZZ + j)*ZZ + hl] * z;
            acc3 += MT[(3*ZZ + j)*ZZ + hl] * z;
        }
        sq[half][0*33 + hl] = acc0;
        sq[half][1*33 + hl] = acc1;
        sq[half][2*33 + hl] = acc2;
        sq[half][3*33 + hl] = acc3;
    }
    wave_lds_fence();
    float qf[32];
#pragma unroll
    for (int j = 0; j < 32; ++j) qf[j] = sq[half][k*33 + j];

    // ---- phase 1: scores+exp -> sum -> alpha (no max pass) ----
    float E[8];
    float sum = 0.f;
    int nit = 0;
    for (int idx = r0 + i; idx < r1; idx += 8, ++nit) {
        int sn = src_by_pos[idx];
        float e = edge_score((const unsigned*)(zGb + (sn*SS + s)*ZZ), qf);
        float ex = __expf(fminf(e, 80.f));
        if (nit < 8) E[nit] = ex;
        sum += ex;
    }
#pragma unroll
    for (int off = 4; off < 32; off <<= 1) sum += __shfl_xor(sum, off);
    float dd = (float)(deg > 1 ? deg : 1);
    float inv = sum > 0.f ? 1.f/(sum*dd) : 0.f;
    nit = 0;
    for (int idx = r0 + i; idx < r1; idx += 8, ++nit) {
        float a = ((nit < 8) ? E[nit]
                 : __expf(fminf(edge_score((const unsigned*)(zGb + (src_by_pos[idx]*SS + s)*ZZ), qf), 80.f))) * inv;
        alpha[(idx*2 + s)*4 + k] = a;
        int jo = idx - r0;
        if (jo < 64) alpha_s[s][jo][k] = a;
    }
    wave_lds_fence();   // LDS-only dep; alpha global stores drain during phase 2

    // ---- phase 2: aggregation, each lane handles h = hl and h+32 ----
    int h = hl;
    const float4 g1a = *(const float4*)(G1 + h*4);
    const float4 g1b = *(const float4*)(G1 + (h+32)*4);
    const float4 g2a = *(const float4*)(G2 + h*4);
    const float4 g2b = *(const float4*)(G2 + (h+32)*4);
    const float4 xd = *(const float4*)(xt + item*4);
    float p2a = c2[h]    + xd.x*g2a.x + xd.y*g2a.y + xd.z*g2a.z + xd.w*g2a.w;
    float p2b = c2[h+32] + xd.x*g2b.x + xd.y*g2b.y + xd.z*g2b.z + xd.w*g2b.w;
    float c1a = c1[h], c1b = c1[h+32];
    float a0 = 0.f, a1 = 0.f, a2 = 0.f, a3 = 0.f;
    float b0 = 0.f, b1 = 0.f, b2 = 0.f, b3 = 0.f;
    int jo = 0;
    for (; jo + 4 <= deg; jo += 4) {
        int sn0 = src_by_pos[r0 + jo];
        int sn1 = src_by_pos[r0 + jo + 1];
        int sn2 = src_by_pos[r0 + jo + 2];
        int sn3 = src_by_pos[r0 + jo + 3];
        float4 x0 = *(const float4*)(xt + (sn0*SS + s)*NIN);
        float4 x1 = *(const float4*)(xt + (sn1*SS + s)*NIN);
        float4 x2 = *(const float4*)(xt + (sn2*SS + s)*NIN);
        float4 x3 = *(const float4*)(xt + (sn3*SS + s)*NIN);
        float4 w0 = (jo+0 < 64) ? *(const float4*)(&alpha_s[s][jo+0][0])
                                : *(const float4*)(alpha + ((r0+jo+0)*2 + s)*4);
        float4 w1 = (jo+1 < 64) ? *(const float4*)(&alpha_s[s][jo+1][0])
                                : *(const float4*)(alpha + ((r0+jo+1)*2 + s)*4);
        float4 w2 = (jo+2 < 64) ? *(const float4*)(&alpha_s[s][jo+2][0])
                                : *(const float4*)(alpha + ((r0+jo+2)*2 + s)*4);
        float4 w3 = (jo+3 < 64) ? *(const float4*)(&alpha_s[s][jo+3][0])
                                : *(const float4*)(alpha + ((r0+jo+3)*2 + s)*4);
        float pa, pb, hda, hdb;
        pa = c1a + x0.x*g1a.x + x0.y*g1a.y + x0.z*g1a.z + x0.w*g1a.w;
        pb = c1b + x0.x*g1b.x + x0.y*g1b.y + x0.z*g1b.z + x0.w*g1b.w;
        hda = pa + p2a; hda = hda > 0.f ? hda : 0.f;
        hdb = pb + p2b; hdb = hdb > 0.f ? hdb : 0.f;
        a0 += w0.x*hda; a1 += w0.y*hda; a2 += w0.z*hda; a3 += w0.w*hda;
        b0 += w0.x*hdb; b1 += w0.y*hdb; b2 += w0.z*hdb; b3 += w0.w*hdb;
        pa = c1a + x1.x*g1a.x + x1.y*g1a.y + x1.z*g1a.z + x1.w*g1a.w;
        pb = c1b + x1.x*g1b.x + x1.y*g1b.y + x1.z*g1b.z + x1.w*g1b.w;
        hda = pa + p2a; hda = hda > 0.f ? hda : 0.f;
        hdb = pb + p2b; hdb = hdb > 0.f ? hdb : 0.f;
        a0 += w1.x*hda; a1 += w1.y*hda; a2 += w1.z*hda; a3 += w1.w*hda;
        b0 += w1.x*hdb; b1 += w1.y*hdb; b2 += w1.z*hdb; b3 += w1.w*hdb;
        pa = c1a + x2.x*g1a.x + x2.y*g1a.y + x2.z*g1a.z + x2.w*g1a.w;
        pb = c1b + x2.x*g1b.x + x2.y*g1b.y + x2.z*g1b.z + x2.w*g1b.w;
        hda = pa + p2a; hda = hda > 0.f ? hda : 0.f;
        hdb = pb + p2b; hdb = hdb > 0.f ? hdb : 0.f;
        a0 += w2.x*hda; a1 += w2.y*hda; a2 += w2.z*hda; a3 += w2.w*hda;
        b0 += w2.x*hdb; b1 += w2.y*hdb; b2 += w2.z*hdb; b3 += w2.w*hdb;
        pa = c1a + x3.x*g1a.x + x3.y*g1a.y + x3.z*g1a.z + x3.w*g1a.w;
        pb = c1b + x3.x*g1b.x + x3.y*g1b.y + x3.z*g1b.z + x3.w*g1b.w;
        hda = pa + p2a; hda = hda > 0.f ? hda : 0.f;
        hdb = pb + p2b; hdb = hdb > 0.f ? hdb : 0.f;
        a0 += w3.x*hda; a1 += w3.y*hda; a2 += w3.z*hda; a3 += w3.w*hda;
        b0 += w3.x*hdb; b1 += w3.y*hdb; b2 += w3.z*hdb; b3 += w3.w*hdb;
    }
    for (; jo < deg; ++jo) {
        int sn = src_by_pos[r0 + jo];
        float4 x0 = *(const float4*)(xt + (sn*SS + s)*NIN);
        float4 w4 = (jo < 64) ? *(const float4*)(&alpha_s[s][jo][0])
                              : *(const float4*)(alpha + ((r0+jo)*2 + s)*4);
        float pa = c1a + x0.x*g1a.x + x0.y*g1a.y + x0.z*g1a.z + x0.w*g1a.w;
        float pb = c1b + x0.x*g1b.x + x0.y*g1b.y + x0.z*g1b.z + x0.w*g1b.w;
        float hda = pa + p2a; hda = hda > 0.f ? hda : 0.f;
        float hdb = pb + p2b; hdb = hdb > 0.f ? hdb : 0.f;
        a0 += w4.x*hda; a1 += w4.y*hda; a2 += w4.z*hda; a3 += w4.w*hda;
        b0 += w4.x*hdb; b1 += w4.y*hdb; b2 += w4.z*hdb; b3 += w4.w*hdb;
    }
    agg_b[item*256 +       h] = f2b(a0);
    agg_b[item*256 + 64  + h] = f2b(a1);
    agg_b[item*256 + 128 + h] = f2b(a2);
    agg_b[item*256 + 192 + h] = f2b(a3);
    agg_b[item*256 +       h+32] = f2b(b0);
    agg_b[item*256 + 64  + h+32] = f2b(b1);
    agg_b[item*256 + 128 + h+32] = f2b(b2);
    agg_b[item*256 + 192 + h+32] = f2b(b3);
}

// B2: fused xenc + edge layer-1 + aggregation (step 1). Same 2-items-per-wave
// lane-split as attn: lanes 0-31 = (n,0), lanes 32-63 = (n,1); each lane
// handles h = hl and h+32.
__global__ __launch_bounds__(64) void k_agg2(
    const float* __restrict__ xt, const float* __restrict__ G1,
    const float* __restrict__ G2, const float* __restrict__ c1,
    const float* __restrict__ c2, const int* __restrict__ src_by_pos,
    const int* __restrict__ offsets, const float* __restrict__ alpha,
    unsigned short* __restrict__ agg_b)
{
    int n = blockIdx.x;
    int l = threadIdx.x;
    int half = l >> 5, hl = l & 31;
    int s = half;
    int item = n*2 + s;
    int r0 = offsets[n], r1 = offsets[n+1];
    int h = hl;
    const float4 g1a = *(const float4*)(G1 + h*4);
    const float4 g1b = *(const float4*)(G1 + (h+32)*4);
    const float4 g2a = *(const float4*)(G2 + h*4);
    const float4 g2b = *(const float4*)(G2 + (h+32)*4);
    const float4 xd = *(const float4*)(xt + item*4);
    float p2a = c2[h]    + xd.x*g2a.x + xd.y*g2a.y + xd.z*g2a.z + xd.w*g2a.w;
    float p2b = c2[h+32] + xd.x*g2b.x + xd.y*g2b.y + xd.z*g2b.z + xd.w*g2b.w;
    float c1a = c1[h], c1b = c1[h+32];
    float a0 = 0.f, a1 = 0.f, a2 = 0.f, a3 = 0.f;
    float b0 = 0.f, b1 = 0.f, b2 = 0.f, b3 = 0.f;
    int idx = r0;
    for (; idx + 4 <= r1; idx += 4) {
        int sn0 = src_by_pos[idx];
        int sn1 = src_by_pos[idx+1];
        int sn2 = src_by_pos[idx+2];
        int sn3 = src_by_pos[idx+3];
        float4 x0 = *(const float4*)(xt + (sn0*SS + s)*NIN);
        float4 x1 = *(const float4*)(xt + (sn1*SS + s)*NIN);
        float4 x2 = *(const float4*)(xt + (sn2*SS + s)*NIN);
        float4 x3 = *(const float4*)(xt + (sn3*SS + s)*NIN);
        float4 w0 = *(const float4*)(alpha + ((idx+0)*2 + s)*4);
        float4 w1 = *(const float4*)(alpha + ((idx+1)*2 + s)*4);
        float4 w2 = *(const float4*)(alpha + ((idx+2)*2 + s)*4);
        float4 w3 = *(const float4*)(alpha + ((idx+3)*2 + s)*4);
        float pa, pb, hda, hdb;
        pa = c1a + x0.x*g1a.x + x0.y*g1a.y + x0.z*g1a.z + x0.w*g1a.w;
        pb = c1b + x0.x*g1b.x + x0.y*g1b.y + x0.z*g1b.z + x0.w*g1b.w;
        hda = pa + p2a; hda = hda > 0.f ? hda : 0.f;
        hdb = pb + p2b; hdb = hdb > 0.f ? hdb : 0.f;
        a0 += w0.x*hda; a1 += w0.y*hda; a2 += w0.z*hda; a3 += w0.w*hda;
        b0 += w0.x*hdb; b1 += w0.y*hdb; b2 += w0.z*hdb; b3 += w0.w*hdb;
        pa = c1a + x1.x*g1a.x + x1.y*g1a.y + x1.z*g1a.z + x1.w*g1a.w;
        pb = c1b + x1.x*g1b.x + x1.y*g1b.y + x1.z*g1b.z + x1.w*g1b.w;
        hda = pa + p2a; hda = hda > 0.f ? hda : 0.f;
        hdb = pb + p2b; hdb = hdb > 0.f ? hdb : 0.f;
        a0 += w1.x*hda; a1 += w1.y*hda; a2 += w1.z*hda; a3 += w1.w*hda;
        b0 += w1.x*hdb; b1 += w1.y*hdb; b2 += w1.z*hdb; b3 += w1.w*hdb;
        pa = c1a + x2.x*g1a.x + x2.y*g1a.y + x2.z*g1a.z + x2.w*g1a.w;
        pb = c1b + x2.x*g1b.x + x2.y*g1b.y + x2.z*g1b.z + x2.w*g1b.w;
        hda = pa + p2a; hda = hda > 0.f ? hda : 0.f;
        hdb = pb + p2b; hdb = hdb > 0.f ? hdb : 0.f;
        a0 += w2.x*hda; a1 += w2.y*hda; a2 += w2.z*hda; a3 += w2.w*hda;
        b0 += w2.x*hdb; b1 += w2.y*hdb; b2 += w2.z*hdb; b3 += w2.w*hdb;
        pa = c1a + x3.x*g1a.x + x3.y*g1a.y + x3.z*g1a.z + x3.w*g1a.w;
        pb = c1b + x3.x*g1b.x + x3.y*g1b.y + x3.z*g1b.z + x3.w*g1b.w;
        hda = pa + p2a; hda = hda > 0.f ? hda : 0.f;
        hdb = pb + p2b; hdb = hdb > 0.f ? hdb : 0.f;
        a0 += w3.x*hda; a1 += w3.y*hda; a2 += w3.z*hda; a3 += w3.w*hda;
        b0 += w3.x*hdb; b1 += w3.y*hdb; b2 += w3.z*hdb; b3 += w3.w*hdb;
    }
    for (; idx < r1; ++idx) {
        int sn = src_by_pos[idx];
        float4 x0 = *(const float4*)(xt + (sn*SS + s)*NIN);
        float4 w0 = *(const float4*)(alpha + (idx*2 + s)*4);
        float pa = c1a + x0.x*g1a.x + x0.y*g1a.y + x0.z*g1a.z + x0.w*g1a.w;
        float pb = c1b + x0.x*g1b.x + x0.y*g1b.y + x0.z*g1b.z + x0.w*g1b.w;
        float hda = pa + p2a; hda = hda > 0.f ? hda : 0.f;
        float hdb = pb + p2b; hdb = hdb > 0.f ? hdb : 0.f;
        a0 += w0.x*hda; a1 += w0.y*hda; a2 += w0.z*hda; a3 += w0.w*hda;
        b0 += w0.x*hdb; b1 += w0.y*hdb; b2 += w0.z*hdb; b3 += w0.w*hdb;
    }
    agg_b[item*256 +       h] = f2b(a0);
    agg_b[item*256 + 64  + h] = f2b(a1);
    agg_b[item*256 + 128 + h] = f2b(a2);
    agg_b[item*256 + 192 + h] = f2b(a3);
    agg_b[item*256 +       h+32] = f2b(b0);
    agg_b[item*256 + 64  + h+32] = f2b(b1);
    agg_b[item*256 + 128 + h+32] = f2b(b2);
    agg_b[item*256 + 192 + h+32] = f2b(b3);
}

// B3: GEMM0 (agg@W2^T block-diag per head) + chained node GEMMs.
// 4 waves/block, 16 items/wave. Per-wave LDS only, no barrier.
__global__ __launch_bounds__(256) void k_node_mfma(
    const unsigned short* __restrict__ agg_b, const unsigned short* __restrict__ zAb,
    const unsigned short* __restrict__ W2b,
    const unsigned short* __restrict__ F1w1b, const unsigned short* __restrict__ F1w2b,
    const unsigned short* __restrict__ ow1b, const unsigned short* __restrict__ ow2b,
    const float* __restrict__ ob1, const float* __restrict__ ob2,
    float* __restrict__ xt, float* __restrict__ out, int tstep)
{
    __shared__ unsigned short res_s[4][16*264];
    __shared__ unsigned short hid_s[4][16*72];
    __shared__ unsigned short hcat_s[4][16*104];
    int tid = threadIdx.x;
    int w = tid >> 6, l = tid & 63, l15 = l & 15, qq = l >> 4;

    bf16x8 w2f[2][4], b2f[2][4], o1f[3][4], bo2[2];
#pragma unroll
    for (int nb = 0; nb < 4; ++nb) {
        int n = nb*16 + l15;
#pragma unroll
        for (int kb = 0; kb < 2; ++kb) {
            w2f[kb][nb] = *(const bf16x8*)(W2b  + n*64 + kb*32 + qq*8);
            b2f[kb][nb] = *(const bf16x8*)(F1w2b + n*64 + kb*32 + qq*8);
        }
#pragma unroll
        for (int kb = 0; kb < 3; ++kb)
            o1f[kb][nb] = *(const bf16x8*)(ow1b + n*96 + kb*32 + qq*8);
    }
#pragma unroll
    for (int kb = 0; kb < 2; ++kb) {
        if (l15 < 4) bo2[kb] = *(const bf16x8*)(ow2b + l15*64 + kb*32 + qq*8);
        else {
            bf16x8 z;
#pragma unroll
            for (int j = 0; j < 8; ++j) z[j] = 0;
            bo2[kb] = z;
        }
    }
    float b1v[4];
#pragma unroll
    for (int nb = 0; nb < 4; ++nb) b1v[nb] = ob1[nb*16 + l15];
    float b2v = (l15 < 4) ? ob2[l15] : 0.0f;

    int itemBase = blockIdx.x*64 + w*16;
    if (itemBase >= NN*SS) return;

    *(uint4*)(&hcat_s[w][l15*104 + 64 + qq*8]) =
        *(const uint4*)(zAb + (itemBase + l15)*ZZ + qq*8);

    // GEMM0: res[item, k*64+h'] = sum_h agg[item,k*64+h] * W2[h'][h]
#pragma unroll
    for (int k = 0; k < 4; ++k) {
        f32x4 acc0[4];
#pragma unroll
        for (int nb = 0; nb < 4; ++nb) acc0[nb] = (f32x4)(0.0f);
#pragma unroll
        for (int kb = 0; kb < 2; ++kb) {
            bf16x8 af = *(const bf16x8*)(agg_b + (itemBase + l15)*256 + k*64 + kb*32 + qq*8);
#pragma unroll
            for (int nb = 0; nb < 4; ++nb)
                acc0[nb] = __builtin_amdgcn_mfma_f32_16x16x32_bf16(af, w2f[kb][nb], acc0[nb], 0, 0, 0);
        }
#pragma unroll
        for (int nb = 0; nb < 4; ++nb)
#pragma unroll
            for (int r = 0; r < 4; ++r)
                res_s[w][(qq*4 + r)*264 + k*64 + nb*16 + l15] = f2b(acc0[nb][r]);
    }

    // GEMM1: res[16x256] @ F1w1^T[256x64], relu
    f32x4 acc[4];
#pragma unroll
    for (int nb = 0; nb < 4; ++nb) acc[nb] = (f32x4)(0.0f);
#pragma unroll
    for (int kb = 0; kb < 8; ++kb) {
        bf16x8 af = *(const bf16x8*)(&res_s[w][l15*264 + kb*32 + qq*8]);
#pragma unroll
        for (int nb = 0; nb < 4; ++nb) {
            bf16x8 bf = *(const bf16x8*)(F1w1b + (nb*16 + l15)*256 + kb*32 + qq*8);
            acc[nb] = __builtin_amdgcn_mfma_f32_16x16x32_bf16(af, bf, acc[nb], 0, 0, 0);
        }
    }
#pragma unroll
    for (int nb = 0; nb < 4; ++nb)
#pragma unroll
        for (int r = 0; r < 4; ++r) {
            float v = acc[nb][r];
            hid_s[w][(qq*4 + r)*72 + nb*16 + l15] = f2b(v > 0.0f ? v : 0.0f);
        }

    // GEMM2: hid[16x64] @ F1w2^T[64x64] -> deltax -> hcat cols 0..63
    f32x4 acc2[4];
#pragma unroll
    for (int nb = 0; nb < 4; ++nb) acc2[nb] = (f32x4)(0.0f);
#pragma unroll
    for (int kb = 0; kb < 2; ++kb) {
        bf16x8 af = *(const bf16x8*)(&hid_s[w][l15*72 + kb*32 + qq*8]);
#pragma unroll
        for (int nb = 0; nb < 4; ++nb)
            acc2[nb] = __builtin_amdgcn_mfma_f32_16x16x32_bf16(af, b2f[kb][nb], acc2[nb], 0, 0, 0);
    }
#pragma unroll
    for (int nb = 0; nb < 4; ++nb)
#pragma unroll
        for (int r = 0; r < 4; ++r)
            hcat_s[w][(qq*4 + r)*104 + nb*16 + l15] = f2b(acc2[nb][r]);

    // GEMM3: hcat[16x96] @ ow1^T[96x64] + b1, relu -> hid_s
    f32x4 acc3[4];
#pragma unroll
    for (int nb = 0; nb < 4; ++nb) acc3[nb] = (f32x4)(0.0f);
#pragma unroll
    for (int kb = 0; kb < 3; ++kb) {
        bf16x8 af = *(const bf16x8*)(&hcat_s[w][l15*104 + kb*32 + qq*8]);
#pragma unroll
        for (int nb = 0; nb < 4; ++nb)
            acc3[nb] = __builtin_amdgcn_mfma_f32_16x16x32_bf16(af, o1f[kb][nb], acc3[nb], 0, 0, 0);
    }
#pragma unroll
    for (int nb = 0; nb < 4; ++nb)
#pragma unroll
        for (int r = 0; r < 4; ++r) {
            float v = acc3[nb][r] + b1v[nb];
            hid_s[w][(qq*4 + r)*72 + nb*16 + l15] = f2b(v > 0.0f ? v : 0.0f);
        }

    // GEMM4: hid[16x64] @ ow2^T[64x4(pad16)] + b2
    f32x4 acc4 = (f32x4)(0.0f);
#pragma unroll
    for (int kb = 0; kb < 2; ++kb) {
        bf16x8 af = *(const bf16x8*)(&hid_s[w][l15*72 + kb*32 + qq*8]);
        acc4 = __builtin_amdgcn_mfma_f32_16x16x32_bf16(af, bo2[kb], acc4, 0, 0, 0);
    }
    if (l15 < 4) {
#pragma unroll
        for (int r = 0; r < 4; ++r) {
            int item = itemBase + qq*4 + r;
            float nx = xt[item*4 + l15] + acc4[r] + b2v;
            xt[item*4 + l15] = nx;
            int n = item >> 1, s = item & 1;
            out[((n*TT + tstep)*SS + s)*4 + l15] = nx;
        }
    }
}

extern "C" void kernel_launch(void* const* d_in, const int* in_sizes, int n_in,
                              void* d_out, int out_size, void* d_ws, size_t ws_size,
                              hipStream_t stream) {
    const float* inputs = (const float*)d_in[0];
    const float* zA     = (const float*)d_in[1];
    const float* zG     = (const float*)d_in[2];
    const int*   src    = (const int*)d_in[3];
    const int*   dst    = (const int*)d_in[4];
    const float* Ws     = (const float*)d_in[5];
    const float* Wd     = (const float*)d_in[6];
    const float* F2w1   = (const float*)d_in[7];
    const float* F2w2   = (const float*)d_in[8];
    const float* F1w1   = (const float*)d_in[9];
    const float* F1w2   = (const float*)d_in[10];
    const float* xw     = (const float*)d_in[11];
    const float* xb     = (const float*)d_in[12];
    const float* ow1    = (const float*)d_in[13];
    const float* ob1    = (const float*)d_in[14];
    const float* ow2    = (const float*)d_in[15];
    const float* ob2    = (const float*)d_in[16];
    float* out = (float*)d_out;

    // ---- workspace carve (units: floats) ----
    float*          base        = (float*)d_ws;
    float*          MT          = base;                              // 4,096
    float*          alpha       = base + 4096;                       // 1,280,000
    int*            deg_i       = (int*)(base + 1284096);            // 10,000 (zeroed)
    int*            offsets     = (int*)(base + 1294096);            // 10,016
    int*            cursor      = (int*)(base + 1304112);            // 10,000
    int*            src_by_pos  = (int*)(base + 1314112);            // 160,000
    float*          xt          = base + 1474112;                    // 80,000
    float*          G1f         = base + 1554112;                    // 256
    float*          G2f         = base + 1554368;                    // 256
    float*          c1f         = base + 1554624;                    // 64
    float*          c2f         = base + 1554688;                    // 64 (pad to 1,554,816)
    unsigned short* W2b         = (unsigned short*)(base + 1554816); // 4,096 ush
    unsigned short* F1w1b       = (unsigned short*)(base + 1556864); // 16,384 ush
    unsigned short* F1w2b       = (unsigned short*)(base + 1565056); // 4,096 ush
    unsigned short* ow1b        = (unsigned short*)(base + 1567104); // 6,144 ush
    unsigned short* ow2b        = (unsigned short*)(base + 1570176); // 256 ush
    unsigned short* zAb         = (unsigned short*)(base + 1570304); // 640,000 ush
    unsigned short* zGb         = (unsigned short*)(base + 1890304); // 640,000 ush
    unsigned short* agg_b       = (unsigned short*)(base + 2210304); // 5,120,000 ush
    // total 4,770,304 floats = 19.1 MB

    hipMemsetAsync(deg_i, 0, 10000u * 4u, stream);

    // ---- attention phase (once) ----
    const int CONVB = (NN*SS*ZZ + 255)/256;   // 2500
    k_prep<<<17 + CONVB, 256, 0, stream>>>(Ws, Wd, F2w1, xw, xb, F2w2, F1w1, F1w2,
                                           ow1, ow2, zA, zG, inputs, dst,
                                           MT, G1f, G2f, c1f, c2f,
                                           W2b, F1w1b, F1w2b, ow1b, ow2b,
                                           zAb, zGb, xt, deg_i);
    k_scan<<<1, 1024, 0, stream>>>(deg_i, offsets, cursor);
    k_scatter<<<(NE + 255)/256, 256, 0, stream>>>(src, dst, cursor, src_by_pos);

    // ---- step 0 (attention fused with aggregation) ----
    k_attn_agg0<<<NN, 64, 0, stream>>>(MT, zG, zGb, src_by_pos, offsets, xt,
                                       G1f, G2f, c1f, c2f, alpha, agg_b);
    k_node_mfma<<<(NN*SS + 63)/64, 256, 0, stream>>>(agg_b, zAb, W2b, F1w1b, F1w2b,
                                                     ow1b, ow2b, ob1, ob2, xt, out, 0);
    // ---- step 1 ----
    k_agg2<<<NN, 64, 0, stream>>>(xt, G1f, G2f, c1f, c2f,
                                  src_by_pos, offsets, alpha, agg_b);
    k_node_mfma<<<(NN*SS + 63)/64, 256, 0, stream>>>(agg_b, zAb, W2b, F1w1b, F1w2b,
                                                     ow1b, ow2b, ob1, ob2, xt, out, 1);
}